// Round 10
// baseline (2804.178 us; speedup 1.0000x reference)
//
#include <hip/hip_runtime.h>

#define NN 4096
#define NE 65536
#define C 256
#define NL 3
#define NH 8
#define DH 32
#define EPS 1e-5f
#define SPLIT 4              // R25: 256-q tiles x SPLIT=4 -> 512 attn items, KT8=8
#define KT8 (NN/128/SPLIT)   // 128-key tiles per split = 8
#define QB 256               // q rows per attn item
#define VS 136               // V LDS row stride in bf16
#define GRID 512             // persistent grid: 2 blocks/CU, co-resident by construction

typedef __bf16 bf16x8 __attribute__((ext_vector_type(8)));
typedef __bf16 bf16x4v __attribute__((ext_vector_type(4)));
typedef float f32x4 __attribute__((ext_vector_type(4)));
typedef short bf16x4s __attribute__((ext_vector_type(4)));   // 4 bf16 as i16x4

// scale * log2(e), folded into Q at projection time so softmax uses exp2
#define QSCALE (0.17677669529663687f * 1.4426950408889634f)

#define CC1 (C*C)            // 65536
#define GS 72                // LDS row stride in bf16 (144 B: 2-way alias, free)

// ---------------- weight prep: fp32 -> bf16; qkv stacked per layer ----------------
// Wb layout (units of CC1): gw1 @0 (3), gw2 @3 (3), qkv @6 (9: layer l at 6+3l,
// order q,k,v), wo @15 (3), mw1 @18 (6), mw2 @24 (6). Total 30 CC1.
__global__ __launch_bounds__(256) void prep_w(const float* __restrict__ s0,
        const float* __restrict__ s1, const float* __restrict__ s2,
        const float* __restrict__ s3, const float* __restrict__ s4,
        const float* __restrict__ s5, const float* __restrict__ s6,
        const float* __restrict__ s7, __bf16* __restrict__ dst) {
    int g = blockIdx.y;
    int i = (blockIdx.x*256 + threadIdx.x)*4;
    const float* src; int n;
    switch (g) {
        case 0: src=s0; n=3*CC1; break;
        case 1: src=s1; n=3*CC1; break;
        case 2: src=s2; n=3*CC1; break;
        case 3: src=s3; n=3*CC1; break;
        case 4: src=s4; n=3*CC1; break;
        case 5: src=s5; n=3*CC1; break;
        case 6: src=s6; n=6*CC1; break;
        default: src=s7; n=6*CC1; break;
    }
    if (i >= n) return;
    size_t off;
    if (g >= 2 && g <= 4) {
        int l = i >> 16, rem = i & (CC1-1);
        off = (size_t)(6 + 3*l + (g-2))*CC1 + rem;
    } else {
        size_t base = (g==0) ? 0 : (g==1) ? 3*(size_t)CC1 : (g==5) ? 15*(size_t)CC1
                    : (g==6) ? 18*(size_t)CC1 : 24*(size_t)CC1;
        off = base + i;
    }
    float4 t = *(const float4*)(src + i);
    bf16x4v o = {(__bf16)t.x, (__bf16)t.y, (__bf16)t.z, (__bf16)t.w};
    *(bf16x4v*)(dst + off) = o;
}

// ---------------- lin1 ----------------
__global__ __launch_bounds__(256) void lin1_kernel(const float* __restrict__ x,
        const float* __restrict__ w, const float* __restrict__ b,
        __bf16* __restrict__ out) {
    int n = blockIdx.x, c = threadIdx.x;
    out[(size_t)n*C + c] = (__bf16)(x[n]*w[c] + b[c]);
}

// ---------------- CSR build ----------------
__global__ __launch_bounds__(256) void hist_kernel(const int* __restrict__ ei,
        int* __restrict__ cnt) {
    int e = blockIdx.x*256 + threadIdx.x;
    atomicAdd(&cnt[ei[NE + e]], 1);
}

__global__ __launch_bounds__(256) void scan_kernel(const int* __restrict__ cnt,
        int* __restrict__ rowptr, int* __restrict__ cursor) {
    __shared__ int tot[256];
    __shared__ int pre[257];
    int t = threadIdx.x;
    int base = t*16;
    int local[16];
    int s = 0;
    #pragma unroll
    for (int i = 0; i < 16; i++) { local[i] = s; s += cnt[base+i]; }
    tot[t] = s;
    __syncthreads();
    if (t == 0) {
        int acc = 0;
        for (int i = 0; i < 256; i++) { pre[i] = acc; acc += tot[i]; }
        pre[256] = acc;
    }
    __syncthreads();
    int off = pre[t];
    #pragma unroll
    for (int i = 0; i < 16; i++) {
        rowptr[base+i] = off + local[i];
        cursor[base+i] = off + local[i];
    }
    if (t == 0) rowptr[NN] = pre[256];
}

__global__ __launch_bounds__(256) void fill_kernel(const int* __restrict__ ei,
        int* __restrict__ cursor, int* __restrict__ eidsrc) {
    int e = blockIdx.x*256 + threadIdx.x;
    int dst = ei[NE + e], src = ei[e];
    int pos = atomicAdd(&cursor[dst], 1);
    eidsrc[pos] = src;
}

// ---------------- hand-rolled grid barrier (R29) ----------------
// Sense-reversing, agent(device)-scope atomics. Arrival: acq_rel RMW on cnt
// (releases this block's prior writes). Master resets cnt then bumps gen
// (acq_rel). Spinners: acquire loads on gen -- each block's acquire emits the
// L1/L2 invalidation on its CU/XCD, so post-barrier plain loads are fresh.
__device__ __forceinline__ void grid_bar(int* cnt, int* gen, int nb) {
    __syncthreads();
    if (threadIdx.x == 0) {
        __threadfence();
        int my = __hip_atomic_load(gen, __ATOMIC_RELAXED, __HIP_MEMORY_SCOPE_AGENT);
        if (__hip_atomic_fetch_add(cnt, 1, __ATOMIC_ACQ_REL, __HIP_MEMORY_SCOPE_AGENT) == nb - 1) {
            __hip_atomic_store(cnt, 0, __ATOMIC_RELAXED, __HIP_MEMORY_SCOPE_AGENT);
            __hip_atomic_fetch_add(gen, 1, __ATOMIC_ACQ_REL, __HIP_MEMORY_SCOPE_AGENT);
        } else {
            while (__hip_atomic_load(gen, __ATOMIC_ACQUIRE, __HIP_MEMORY_SCOPE_AGENT) == my)
                __builtin_amdgcn_s_sleep(8);
        }
        __threadfence();
    }
    __syncthreads();
}

// ---------------- GEMM core, BK=64, register-prefetch staging (R27) ----------------
// Block-index free; every iteration ends with __syncthreads() so back-to-back
// invocations by a persistent block are race-free.
template<int QKV, int BN, int COMB>
__device__ __forceinline__ void gemm_core(int bm, int bn,
        const __bf16* A, const float* A2f, const __bf16* A2b, const __bf16* W,
        const float* b0, const float* b1, const float* b2,
        const __bf16* add1, const __bf16* add2,
        __bf16* out, __bf16* vt, __bf16* ktp, float* stats,
        const float* coefs,    // LDS coef table (BN==1)
        const float* st1, const float* g1, const float* bb1,
        const float* st2, const float* g2, const float* bb2,   // BN==2
        const float* lsum,     // COMB
        int K, int Nout, int relu, __bf16* As, __bf16* Ws) {
    int tid = threadIdx.x;
    int wave = tid >> 6, lane = tid & 63;
    int ln = lane & 15, quad = lane >> 4;
    int row = tid >> 2, kseg = (tid & 3) * 16;
    f32x4 acc[4] = {};
    bf16x8 pa0, pa1, pw0, pw1, pz0, pz1;
    float4 pf0, pf1, pf2, pf3;
    bf16x8 pc0[SPLIT], pc1[SPLIT];
    float pwt[SPLIT];
    auto prefetch = [&](int k0) {
        if constexpr (COMB) {
            int rowg = bm + row;
            int head = (k0 + kseg) >> 5;
            #pragma unroll
            for (int zz = 0; zz < SPLIT; zz++) {
                pwt[zz] = lsum[((size_t)zz*NH + head)*NN + rowg];
                const __bf16* p = &A[((size_t)zz*NN + rowg)*C + k0 + kseg];
                pc0[zz] = *(const bf16x8*)p;
                pc1[zz] = *(const bf16x8*)(p + 8);
            }
        } else {
            const __bf16* ap = &A[(size_t)(bm+row)*K + k0 + kseg];
            pa0 = *(const bf16x8*)ap;
            pa1 = *(const bf16x8*)(ap + 8);
            if constexpr (BN == 1) {
                const __bf16* p = &A2b[(size_t)(bm+row)*K + k0 + kseg];
                pz0 = *(const bf16x8*)p;
                pz1 = *(const bf16x8*)(p + 8);
            } else if (A2f) {
                const float* p = &A2f[(size_t)(bm+row)*K + k0 + kseg];
                pf0 = *(const float4*)p;
                pf1 = *(const float4*)(p+4);
                pf2 = *(const float4*)(p+8);
                pf3 = *(const float4*)(p+12);
            }
        }
        const __bf16* wp = &W[(size_t)(bn+row)*K + k0 + kseg];
        pw0 = *(const bf16x8*)wp;
        pw1 = *(const bf16x8*)(wp + 8);
    };
    prefetch(0);
    for (int k0 = 0; k0 < K; k0 += 64) {
        {   // transform prefetched regs and commit to LDS
            bf16x8 a0, a1;
            if constexpr (COMB) {
                float tot = 0.f;
                #pragma unroll
                for (int zz = 0; zz < SPLIT; zz++) tot += pwt[zz];
                float inv = 1.0f / tot;
                float v[16] = {};
                #pragma unroll
                for (int zz = 0; zz < SPLIT; zz++) {
                    #pragma unroll
                    for (int j = 0; j < 8; j++) {
                        v[j]   += pwt[zz]*(float)pc0[zz][j];
                        v[8+j] += pwt[zz]*(float)pc1[zz][j];
                    }
                }
                #pragma unroll
                for (int j = 0; j < 8; j++) {
                    a0[j] = (__bf16)(v[j]*inv);
                    a1[j] = (__bf16)(v[8+j]*inv);
                }
            } else {
                a0 = pa0;
                a1 = pa1;
                if constexpr (BN == 1) {
                    float sc1[16], sh1[16], sc2[16], sh2[16];
                    #pragma unroll
                    for (int i = 0; i < 4; i++) {
                        *(float4*)&sc1[i*4] = *(const float4*)&coefs[k0 + kseg + i*4];
                        *(float4*)&sh1[i*4] = *(const float4*)&coefs[C + k0 + kseg + i*4];
                        *(float4*)&sc2[i*4] = *(const float4*)&coefs[2*C + k0 + kseg + i*4];
                        *(float4*)&sh2[i*4] = *(const float4*)&coefs[3*C + k0 + kseg + i*4];
                    }
                    #pragma unroll
                    for (int j = 0; j < 8; j++) {
                        a0[j] = (__bf16)((float)a0[j]*sc1[j] + sh1[j]
                                       + (float)pz0[j]*sc2[j] + sh2[j]);
                        a1[j] = (__bf16)((float)a1[j]*sc1[8+j] + sh1[8+j]
                                       + (float)pz1[j]*sc2[8+j] + sh2[8+j]);
                    }
                } else if (A2f) {
                    a0[0]=(__bf16)((float)a0[0]+pf0.x); a0[1]=(__bf16)((float)a0[1]+pf0.y);
                    a0[2]=(__bf16)((float)a0[2]+pf0.z); a0[3]=(__bf16)((float)a0[3]+pf0.w);
                    a0[4]=(__bf16)((float)a0[4]+pf1.x); a0[5]=(__bf16)((float)a0[5]+pf1.y);
                    a0[6]=(__bf16)((float)a0[6]+pf1.z); a0[7]=(__bf16)((float)a0[7]+pf1.w);
                    a1[0]=(__bf16)((float)a1[0]+pf2.x); a1[1]=(__bf16)((float)a1[1]+pf2.y);
                    a1[2]=(__bf16)((float)a1[2]+pf2.z); a1[3]=(__bf16)((float)a1[3]+pf2.w);
                    a1[4]=(__bf16)((float)a1[4]+pf3.x); a1[5]=(__bf16)((float)a1[5]+pf3.y);
                    a1[6]=(__bf16)((float)a1[6]+pf3.z); a1[7]=(__bf16)((float)a1[7]+pf3.w);
                }
            }
            *(bf16x8*)&As[row*GS + kseg]     = a0;
            *(bf16x8*)&As[row*GS + kseg + 8] = a1;
            *(bf16x8*)&Ws[row*GS + kseg]     = pw0;
            *(bf16x8*)&Ws[row*GS + kseg + 8] = pw1;
        }
        __syncthreads();
        if (k0 + 64 < K) prefetch(k0 + 64);   // VMEM issues overlap MFMA below
        #pragma unroll
        for (int kt2 = 0; kt2 < 2; kt2++) {
            bf16x8 bfr = *(const bf16x8*)&Ws[(wave*16+ln)*GS + kt2*32 + quad*8];
            #pragma unroll
            for (int i = 0; i < 4; i++) {
                bf16x8 afr = *(const bf16x8*)&As[(i*16+ln)*GS + kt2*32 + quad*8];
                acc[i] = __builtin_amdgcn_mfma_f32_16x16x32_bf16(afr, bfr, acc[i], 0, 0, 0);
            }
        }
        __syncthreads();                      // LDS reads done before next write
    }
    int col = bn + wave*16 + ln;
    if constexpr (QKV) {
        float bsv = col < 256 ? b0[col] : (col < 512 ? b1[col-256] : b2[col-512]);
        if (col < 256) {
            #pragma unroll
            for (int i = 0; i < 4; i++)
                #pragma unroll
                for (int rr = 0; rr < 4; rr++)
                    out[(size_t)(bm + i*16 + quad*4 + rr)*C + col] =
                        (__bf16)((acc[i][rr] + bsv) * (float)QSCALE);
        } else if (col < 512) {
            int hd = (col-256) >> 5, dh = (col-256) & 31;
            #pragma unroll
            for (int i = 0; i < 4; i++)
                #pragma unroll
                for (int rr = 0; rr < 4; rr++)
                    ktp[((size_t)hd*NN + bm + i*16 + quad*4 + rr)*DH + dh] =
                        (__bf16)(acc[i][rr] + bsv);
        } else {
            int vrow = col - 512;
            #pragma unroll
            for (int i = 0; i < 4; i++) {
                bf16x4v pk = {(__bf16)(acc[i][0]+bsv), (__bf16)(acc[i][1]+bsv),
                              (__bf16)(acc[i][2]+bsv), (__bf16)(acc[i][3]+bsv)};
                *(bf16x4v*)&vt[(size_t)vrow*NN + bm + i*16 + quad*4] = pk;
            }
        }
        return;
    }
    float bsv = b0[col];
    float sc1 = 0.f, sh1 = 0.f, sc2 = 0.f, sh2 = 0.f;
    if constexpr (BN == 2) {
        float m1 = st1[col]*(1.f/NN);
        sc1 = rsqrtf(st1[C+col]*(1.f/NN) - m1*m1 + EPS) * g1[col];
        sh1 = bb1[col] - m1*sc1;
        float m2 = st2[col]*(1.f/NN);
        sc2 = rsqrtf(st2[C+col]*(1.f/NN) - m2*m2 + EPS) * g2[col];
        sh2 = bb2[col] - m2*sc2;
    }
    float ssum = 0.f, ssq = 0.f;
    #pragma unroll
    for (int i = 0; i < 4; i++) {
        #pragma unroll
        for (int rr = 0; rr < 4; rr++) {
            int rw = bm + i*16 + quad*4 + rr;
            float vv = acc[i][rr] + bsv;
            if (relu) vv = fmaxf(vv, 0.f);
            size_t idx = (size_t)rw*Nout + col;
            if constexpr (BN == 2) {
                vv += (float)add1[idx]*sc1 + sh1 + (float)add2[idx]*sc2 + sh2;
            } else {
                if (add1) vv += (float)add1[idx];
                if (add2) vv += (float)add2[idx];
            }
            out[idx] = (__bf16)vv;
            ssum += vv; ssq += vv*vv;
        }
    }
    if (stats) {
        ssum += __shfl_xor(ssum, 16); ssum += __shfl_xor(ssum, 32);
        ssq  += __shfl_xor(ssq, 16);  ssq  += __shfl_xor(ssq, 32);
        if (quad == 0) {
            atomicAdd(&stats[col], ssum);
            atomicAdd(&stats[Nout + col], ssq);
        }
    }
}

// ---------------- attention body: 256-q tiles, SPLIT=4 (R25, unchanged) ----------------
__device__ __forceinline__ void attn_body(int t, const __bf16* __restrict__ qbuf,
        const __bf16* __restrict__ kt, const __bf16* __restrict__ vt,
        __bf16* __restrict__ opart, float* __restrict__ lsum, __bf16* lds) {
    int head = t & 7, qi = (t >> 3) & 15, z = t >> 7;
    int qb = qi * QB;
    int hb = head * DH;
    int tid = threadIdx.x;
    int wave = tid >> 6, lane = tid & 63;
    int ln = lane & 15, quad = lane >> 4;
    __bf16* Kb0 = lds;                    // [128][36] = 4608 elems each
    __bf16* Kb1 = lds + 4608;
    __bf16* Vb0 = lds + 9216;             // [32][VS] = 4352 elems each
    __bf16* Vb1 = lds + 9216 + 32*VS;

    bf16x8 qf[4];
    #pragma unroll
    for (int g = 0; g < 4; g++)
        qf[g] = *(const bf16x8*)&qbuf[(size_t)(qb + wave*64 + g*16 + ln)*C + hb + quad*8];

    f32x4 ot[4][2] = {};
    f32x4 la[4] = {};
    const bf16x4s ones = {(short)0x3F80, (short)0x3F80, (short)0x3F80, (short)0x3F80};
    const f32x4 zz = {0.f,0.f,0.f,0.f};

    int srow = tid >> 1, sseg = (tid & 1) * 16;   // K staging: 2 threads/row (64B rows)
    int vd = tid >> 3, vseg = (tid & 7) * 16;     // V staging: 8 threads/dim-row
    int kt0 = z * KT8;
    const __bf16* kbase = &kt[(size_t)head*NN*DH];
    {   // prologue: stage tile (rotated start decorrelates VMEM bursts)
        int i0 = qi & (KT8-1);
        const __bf16* kp = &kbase[(size_t)((kt0+i0)*128 + srow)*DH + sseg];
        *(bf16x8*)&Kb0[srow*36 + sseg]     = *(const bf16x8*)kp;
        *(bf16x8*)&Kb0[srow*36 + sseg + 8] = *(const bf16x8*)(kp + 8);
        const __bf16* vp = &vt[(size_t)(hb + vd)*NN + (kt0+i0)*128 + vseg];
        *(bf16x8*)&Vb0[vd*VS + vseg]     = *(const bf16x8*)vp;
        *(bf16x8*)&Vb0[vd*VS + vseg + 8] = *(const bf16x8*)(vp + 8);
    }
    for (int ii = 0; ii < KT8; ii++) {
        int inext = (ii + 1 + qi) & (KT8-1);
        __bf16* Kc = (ii & 1) ? Kb1 : Kb0;
        __bf16* Kn = (ii & 1) ? Kb0 : Kb1;
        __bf16* Vc = (ii & 1) ? Vb1 : Vb0;
        __bf16* Vn = (ii & 1) ? Vb0 : Vb1;
        __syncthreads();                       // Kc/Vc writes visible
        bf16x8 nk0, nk1, nv0, nv1;
        bool hasNext = (ii + 1 < KT8);
        if (hasNext) {                          // next-tile loads overlap compute
            const __bf16* kp = &kbase[(size_t)((kt0+inext)*128 + srow)*DH + sseg];
            nk0 = *(const bf16x8*)kp;
            nk1 = *(const bf16x8*)(kp + 8);
            const __bf16* vp = &vt[(size_t)(hb + vd)*NN + (kt0+inext)*128 + vseg];
            nv0 = *(const bf16x8*)vp;
            nv1 = *(const bf16x8*)(vp + 8);
        }
        #pragma unroll
        for (int pr = 0; pr < 4; pr++) {
            #pragma unroll
            for (int s = 0; s < 2; s++) {
                int ks = pr*2 + s;
                bf16x8 kf = *(const bf16x8*)&Kc[(ks*16+ln)*36 + quad*8];
                bf16x4s vf0 = *(const bf16x4s*)&Vc[(0*16+ln)*VS + ks*16 + quad*4];
                bf16x4s vf1 = *(const bf16x4s*)&Vc[(1*16+ln)*VS + ks*16 + quad*4];
                f32x4 st0 = __builtin_amdgcn_mfma_f32_16x16x32_bf16(kf, qf[0], zz, 0, 0, 0);
                f32x4 st1 = __builtin_amdgcn_mfma_f32_16x16x32_bf16(kf, qf[1], zz, 0, 0, 0);
                f32x4 st2 = __builtin_amdgcn_mfma_f32_16x16x32_bf16(kf, qf[2], zz, 0, 0, 0);
                f32x4 st3 = __builtin_amdgcn_mfma_f32_16x16x32_bf16(kf, qf[3], zz, 0, 0, 0);
                union { __bf16 b[4]; bf16x4s s; } pf0, pf1, pf2, pf3;
                #pragma unroll
                for (int rr = 0; rr < 4; rr++) {
                    pf0.b[rr] = (__bf16)__builtin_amdgcn_exp2f(st0[rr]);
                    pf1.b[rr] = (__bf16)__builtin_amdgcn_exp2f(st1[rr]);
                    pf2.b[rr] = (__bf16)__builtin_amdgcn_exp2f(st2[rr]);
                    pf3.b[rr] = (__bf16)__builtin_amdgcn_exp2f(st3[rr]);
                }
                ot[0][0] = __builtin_amdgcn_mfma_f32_16x16x16bf16_1k(vf0, pf0.s, ot[0][0], 0, 0, 0);
                ot[0][1] = __builtin_amdgcn_mfma_f32_16x16x16bf16_1k(vf1, pf0.s, ot[0][1], 0, 0, 0);
                ot[1][0] = __builtin_amdgcn_mfma_f32_16x16x16bf16_1k(vf0, pf1.s, ot[1][0], 0, 0, 0);
                ot[1][1] = __builtin_amdgcn_mfma_f32_16x16x16bf16_1k(vf1, pf1.s, ot[1][1], 0, 0, 0);
                ot[2][0] = __builtin_amdgcn_mfma_f32_16x16x16bf16_1k(vf0, pf2.s, ot[2][0], 0, 0, 0);
                ot[2][1] = __builtin_amdgcn_mfma_f32_16x16x16bf16_1k(vf1, pf2.s, ot[2][1], 0, 0, 0);
                ot[3][0] = __builtin_amdgcn_mfma_f32_16x16x16bf16_1k(vf0, pf3.s, ot[3][0], 0, 0, 0);
                ot[3][1] = __builtin_amdgcn_mfma_f32_16x16x16bf16_1k(vf1, pf3.s, ot[3][1], 0, 0, 0);
                la[0]    = __builtin_amdgcn_mfma_f32_16x16x16bf16_1k(ones, pf0.s, la[0], 0, 0, 0);
                la[1]    = __builtin_amdgcn_mfma_f32_16x16x16bf16_1k(ones, pf1.s, la[1], 0, 0, 0);
                la[2]    = __builtin_amdgcn_mfma_f32_16x16x16bf16_1k(ones, pf2.s, la[2], 0, 0, 0);
                la[3]    = __builtin_amdgcn_mfma_f32_16x16x16bf16_1k(ones, pf3.s, la[3], 0, 0, 0);
            }
        }
        if (hasNext) {
            *(bf16x8*)&Kn[srow*36 + sseg]     = nk0;
            *(bf16x8*)&Kn[srow*36 + sseg + 8] = nk1;
            *(bf16x8*)&Vn[vd*VS + vseg]     = nv0;
            *(bf16x8*)&Vn[vd*VS + vseg + 8] = nv1;
        }
    }
    #pragma unroll
    for (int g = 0; g < 4; g++) {
        float l_ = la[g][0];
        float inv = 1.0f / l_;
        int qrow = qb + wave*64 + g*16 + ln;
        #pragma unroll
        for (int h = 0; h < 2; h++) {
            bf16x4v pk = {(__bf16)(ot[g][h][0]*inv), (__bf16)(ot[g][h][1]*inv),
                          (__bf16)(ot[g][h][2]*inv), (__bf16)(ot[g][h][3]*inv)};
            *(bf16x4v*)&opart[((size_t)z*NN + qrow)*C + hb + h*16 + quad*4] = pk;
        }
        if (quad == 0)
            lsum[((size_t)z*NH + head)*NN + qrow] = l_;
    }
}

// ---------------- per-item helpers for the fused kernel ----------------
__device__ __forceinline__ void agg_item(int grp, const __bf16* __restrict__ Hb,
        const int* __restrict__ rowptr, const int* __restrict__ eidsrc,
        float* __restrict__ agg) {
    int tid = threadIdx.x;
    int wave = tid >> 6, lane = tid & 63;
    int node = grp*4 + wave;
    int beg = rowptr[node], end = rowptr[node+1];
    float s0 = 0.f, s1 = 0.f, s2 = 0.f, s3 = 0.f;
    for (int e = beg; e < end; e++) {
        int src = eidsrc[e];
        bf16x4v hv = *(const bf16x4v*)&Hb[(size_t)src*C + lane*4];
        s0 += (float)hv[0]; s1 += (float)hv[1];
        s2 += (float)hv[2]; s3 += (float)hv[3];
    }
    float4 o = {s0, s1, s2, s3};
    *(float4*)&agg[(size_t)node*C + lane*4] = o;
}

__device__ __forceinline__ void bn_item(int it, const __bf16* __restrict__ z,
        const float* __restrict__ stats, const float* __restrict__ g,
        const float* __restrict__ b, __bf16* __restrict__ outb,
        float* __restrict__ outf) {
    int idx4 = (it*256 + threadIdx.x) * 4;
    int c = idx4 & (C-1);
    bf16x4v zv = *(const bf16x4v*)&z[idx4];
    float4 st = *(const float4*)&stats[c];
    float4 sq = *(const float4*)&stats[C + c];
    float4 gv = *(const float4*)&g[c];
    float4 bv = *(const float4*)&b[c];
    float o[4];
    float m0 = st.x*(1.f/NN), m1 = st.y*(1.f/NN), m2 = st.z*(1.f/NN), m3 = st.w*(1.f/NN);
    o[0] = ((float)zv[0] - m0) * rsqrtf(sq.x*(1.f/NN) - m0*m0 + EPS) * gv.x + bv.x;
    o[1] = ((float)zv[1] - m1) * rsqrtf(sq.y*(1.f/NN) - m1*m1 + EPS) * gv.y + bv.y;
    o[2] = ((float)zv[2] - m2) * rsqrtf(sq.z*(1.f/NN) - m2*m2 + EPS) * gv.z + bv.z;
    o[3] = ((float)zv[3] - m3) * rsqrtf(sq.w*(1.f/NN) - m3*m3 + EPS) * gv.w + bv.w;
    if (outb) {
        bf16x4v ov = {(__bf16)o[0], (__bf16)o[1], (__bf16)o[2], (__bf16)o[3]};
        *(bf16x4v*)&outb[idx4] = ov;
    } else {
        float4 ov = {o[0], o[1], o[2], o[3]};
        *(float4*)&outf[idx4] = ov;
    }
}

// ---------------- R29: fused 3-layer persistent kernel, hand-rolled barrier ----------
// R28's coop launch appears to have been silently rejected under graph capture
// (absmax == max|ref| => output never written). Same fused structure, but
// ordinary launch + sense-reversing global barrier (agent-scope atomics).
// 512 blocks, 40KB LDS, launch_bounds(256,2) -> 2/CU, all co-resident.
struct GArgs {
    const __bf16* Wb;
    __bf16 *Hb, *z1, *zbuf3, *z2, *t1, *Qbuf, *Ktb, *Vt, *hiddenb, *Opart;
    float *agg, *stats, *lsum;
    const int *rowptr, *eidsrc;
    const float *gin_b1, *gin_b2, *bq, *bk, *bv, *bo;
    const float *bn1_g, *bn1_b, *bn2_g, *bn2_b, *bn3_g, *bn3_b;
    const float *mb1, *mb2;
    float* outf;
    int *bcnt, *bgen;
};

__global__ __launch_bounds__(256, 2) void layers_kernel(GArgs a) {
    __shared__ __bf16 lds[17920];     // attn 17920; gemm uses first 9216
    __shared__ float coefs[4*C];
    int bid = blockIdx.x;
    int tid = threadIdx.x;
    for (int l = 0; l < NL; l++) {
        const __bf16* gw1b = a.Wb + (size_t)l*CC1;
        const __bf16* gw2b = a.Wb + (size_t)(3+l)*CC1;
        const __bf16* wqkv = a.Wb + (size_t)(6+3*l)*CC1;
        const __bf16* wop  = a.Wb + (size_t)(15+l)*CC1;
        const __bf16* mw1p = a.Wb + (size_t)(18+2*l)*CC1;
        const __bf16* mw2p = a.Wb + (size_t)(24+2*l)*CC1;
        const float* gb1 = a.gin_b1 + (size_t)l*C;
        const float* gb2 = a.gin_b2 + (size_t)l*C;
        const float* lbq = a.bq + (size_t)l*C;
        const float* lbk = a.bk + (size_t)l*C;
        const float* lbv = a.bv + (size_t)l*C;
        const float* lbo = a.bo + (size_t)l*C;
        const float* lmb1 = a.mb1 + (size_t)l*2*C;
        const float* lmb2 = a.mb2 + (size_t)l*C;
        float* st1 = a.stats + (size_t)l*3*2*C;
        float* st2 = st1 + 2*C;
        float* st3 = st2 + 2*C;
        const float* g1v = a.bn1_g + (size_t)l*C; const float* b1v = a.bn1_b + (size_t)l*C;
        const float* g2v = a.bn2_g + (size_t)l*C; const float* b2v = a.bn2_b + (size_t)l*C;
        const float* g3v = a.bn3_g + (size_t)l*C; const float* b3v = a.bn3_b + (size_t)l*C;

        // ---- P1: QKV gemm (768 tiles) + CSR gather agg (1024 groups), balanced ----
        if (bid < 256) {      // 2 gemm tiles each
            #pragma unroll
            for (int j = 0; j < 2; j++) {
                int it = bid*2 + j;
                gemm_core<1,0,0>((it & 63)*64, (it >> 6)*64, a.Hb, nullptr, nullptr, wqkv,
                        lbq, lbk, lbv, nullptr, nullptr, a.Qbuf, a.Vt, a.Ktb, nullptr,
                        nullptr, nullptr, nullptr, nullptr, nullptr, nullptr, nullptr,
                        nullptr, C, 768, 0, lds, lds + 4608);
            }
        } else {              // 1 gemm tile + 4 agg groups
            int it = 512 + (bid - 256);
            gemm_core<1,0,0>((it & 63)*64, (it >> 6)*64, a.Hb, nullptr, nullptr, wqkv,
                    lbq, lbk, lbv, nullptr, nullptr, a.Qbuf, a.Vt, a.Ktb, nullptr,
                    nullptr, nullptr, nullptr, nullptr, nullptr, nullptr, nullptr,
                    nullptr, C, 768, 0, lds, lds + 4608);
            #pragma unroll
            for (int j = 0; j < 4; j++)
                agg_item((bid - 256)*4 + j, a.Hb, a.rowptr, a.eidsrc, a.agg);
        }
        grid_bar(a.bcnt, a.bgen, GRID);

        // ---- P2: GIN gemm1 (256) + attention (512) ----
        for (int it = bid; it < 768; it += GRID) {
            if (it < 256)
                gemm_core<0,0,0>((it >> 2)*64, (it & 3)*64, a.Hb, a.agg, nullptr, gw1b,
                        gb1, nullptr, nullptr, nullptr, nullptr, a.t1, nullptr, nullptr,
                        nullptr, nullptr, nullptr, nullptr, nullptr, nullptr, nullptr,
                        nullptr, nullptr, C, C, 1, lds, lds + 4608);
            else
                attn_body(it - 256, a.Qbuf, a.Ktb, a.Vt, a.Opart, a.lsum, lds);
        }
        grid_bar(a.bcnt, a.bgen, GRID);

        // ---- P3: GIN gemm2 (256) + proj-with-combine (256) ----
        if (bid < 256)
            gemm_core<0,0,0>((bid >> 2)*64, (bid & 3)*64, a.t1, nullptr, nullptr, gw2b,
                    gb2, nullptr, nullptr, a.Hb, nullptr, a.z1, nullptr, nullptr, st1,
                    nullptr, nullptr, nullptr, nullptr, nullptr, nullptr, nullptr,
                    nullptr, C, C, 0, lds, lds + 4608);
        else {
            int t2 = bid - 256;
            gemm_core<0,0,1>((t2 >> 2)*64, (t2 & 3)*64, a.Opart, nullptr, nullptr, wop,
                    lbo, nullptr, nullptr, a.Hb, nullptr, a.z2, nullptr, nullptr, st2,
                    nullptr, nullptr, nullptr, nullptr, nullptr, nullptr, nullptr,
                    a.lsum, C, C, 0, lds, lds + 4608);
        }
        grid_bar(a.bcnt, a.bgen, GRID);

        // ---- P4: ff1 (512), bn1/bn2 folded into staging via LDS coefs ----
        {
            float m = st1[tid]*(1.f/NN);
            float var = st1[C+tid]*(1.f/NN) - m*m;
            float s = rsqrtf(var + EPS) * g1v[tid];
            coefs[tid] = s; coefs[C+tid] = b1v[tid] - m*s;
            m = st2[tid]*(1.f/NN);
            var = st2[C+tid]*(1.f/NN) - m*m;
            s = rsqrtf(var + EPS) * g2v[tid];
            coefs[2*C+tid] = s; coefs[3*C+tid] = b2v[tid] - m*s;
            __syncthreads();
            gemm_core<0,1,0>((bid >> 3)*64, (bid & 7)*64, a.z1, nullptr, a.z2, mw1p,
                    lmb1, nullptr, nullptr, nullptr, nullptr, a.hiddenb, nullptr, nullptr,
                    nullptr, coefs, nullptr, nullptr, nullptr, nullptr, nullptr, nullptr,
                    nullptr, C, 2*C, 1, lds, lds + 4608);
        }
        grid_bar(a.bcnt, a.bgen, GRID);

        // ---- P5: ff2 (256), bn residuals in epilogue ----
        if (bid < 256)
            gemm_core<0,2,0>((bid >> 2)*64, (bid & 3)*64, a.hiddenb, nullptr, nullptr, mw2p,
                    lmb2, nullptr, nullptr, a.z1, a.z2, a.zbuf3, nullptr, nullptr, st3,
                    nullptr, st1, g1v, b1v, st2, g2v, b2v,
                    nullptr, 2*C, C, 0, lds, lds + 4608);
        grid_bar(a.bcnt, a.bgen, GRID);

        // ---- P6: bn3 apply (1024 items) ----
        for (int it = bid; it < 1024; it += GRID) {
            if (l == NL-1) bn_item(it, a.zbuf3, st3, g3v, b3v, nullptr, a.outf);
            else           bn_item(it, a.zbuf3, st3, g3v, b3v, a.Hb, nullptr);
        }
        if (l < NL-1) grid_bar(a.bcnt, a.bgen, GRID);
    }
}

extern "C" void kernel_launch(void* const* d_in, const int* in_sizes, int n_in,
                              void* d_out, int out_size, void* d_ws, size_t ws_size,
                              hipStream_t stream) {
    const float* x      = (const float*)d_in[0];
    const int*   ei     = (const int*)d_in[1];
    const float* lin1_w = (const float*)d_in[2];
    const float* lin1_b = (const float*)d_in[3];
    const float* gin_w1 = (const float*)d_in[4];
    const float* gin_b1 = (const float*)d_in[5];
    const float* gin_w2 = (const float*)d_in[6];
    const float* gin_b2 = (const float*)d_in[7];
    const float* wq = (const float*)d_in[8];
    const float* wk = (const float*)d_in[9];
    const float* wv = (const float*)d_in[10];
    const float* wo = (const float*)d_in[11];
    const float* bq = (const float*)d_in[12];
    const float* bk = (const float*)d_in[13];
    const float* bv = (const float*)d_in[14];
    const float* bo = (const float*)d_in[15];
    const float* bn1_g = (const float*)d_in[16];
    const float* bn1_b = (const float*)d_in[17];
    const float* bn2_g = (const float*)d_in[18];
    const float* bn2_b = (const float*)d_in[19];
    const float* bn3_g = (const float*)d_in[20];
    const float* bn3_b = (const float*)d_in[21];
    const float* mw1 = (const float*)d_in[22];
    const float* mb1 = (const float*)d_in[23];
    const float* mw2 = (const float*)d_in[24];
    const float* mb2 = (const float*)d_in[25];

    const size_t MB = 1u << 20;
    char* ws = (char*)d_ws;
    __bf16* Hb      = (__bf16*)(ws);            // 2 MB  layer input
    __bf16* z1      = (__bf16*)(ws + 2*MB);     // 2 MB  GIN pre-bn1
    __bf16* zbuf3   = (__bf16*)(ws + 4*MB);     // 2 MB  pre-bn3
    __bf16* z2      = (__bf16*)(ws + 6*MB);     // 2 MB  attn pre-bn2
    __bf16* t1      = (__bf16*)(ws + 8*MB);     // 2 MB  GIN hidden
    __bf16* Qbuf    = (__bf16*)(ws + 10*MB);    // 2 MB  [N][C] (QSCALE folded)
    __bf16* Ktb     = (__bf16*)(ws + 12*MB);    // 2 MB  [NH][NN][DH] head-major K
    __bf16* Vt      = (__bf16*)(ws + 14*MB);    // 2 MB  [C][N]
    float*  agg     = (float*)(ws + 16*MB);     // 4 MB  (dead after P2)
    __bf16* hiddenb = (__bf16*)(ws + 16*MB);    // 4 MB  shares agg region (agg dead
                                                //       after P2; hidden lives P4->P5)
    __bf16* Opart   = (__bf16*)(ws + 20*MB);    // 8 MB  (SPLIT=4)
    __bf16* Wb      = (__bf16*)(ws + 28*MB);    // 3.93 MB
    float*  stats   = (float*)(ws + 32*MB);     // 9 x 2C
    int*    cursor  = (int*)(ws + 32*MB + 64*1024);
    int*    rowptr  = (int*)(ws + 32*MB + 96*1024);
    int*    eidsrc  = (int*)(ws + 32*MB + 128*1024);
    float*  lsum    = (float*)(ws + 33*MB);     // 0.5 MB (SPLIT=4), dedicated
    int*    barp    = (int*)(ws + 33*MB + 512*1024);   // 8B grid-barrier state

    dim3 blk(256);

    prep_w<<<dim3(384, 8), blk, 0, stream>>>(gin_w1, gin_w2, wq, wk, wv, wo, mw1, mw2, Wb);
    hipMemsetAsync(stats, 0, 9 * 2 * C * sizeof(float), stream);
    hipMemsetAsync(barp, 0, 2 * sizeof(int), stream);
    lin1_kernel<<<NN, blk, 0, stream>>>(x, lin1_w, lin1_b, Hb);
    hipMemsetAsync(cursor, 0, NN * sizeof(int), stream);
    hist_kernel<<<NE/256, blk, 0, stream>>>(ei, cursor);
    scan_kernel<<<1, blk, 0, stream>>>(cursor, rowptr, cursor);
    fill_kernel<<<NE/256, blk, 0, stream>>>(ei, cursor, eidsrc);

    GArgs ga;
    ga.Wb = Wb;
    ga.Hb = Hb; ga.z1 = z1; ga.zbuf3 = zbuf3; ga.z2 = z2; ga.t1 = t1;
    ga.Qbuf = Qbuf; ga.Ktb = Ktb; ga.Vt = Vt; ga.hiddenb = hiddenb; ga.Opart = Opart;
    ga.agg = agg; ga.stats = stats; ga.lsum = lsum;
    ga.rowptr = rowptr; ga.eidsrc = eidsrc;
    ga.gin_b1 = gin_b1; ga.gin_b2 = gin_b2;
    ga.bq = bq; ga.bk = bk; ga.bv = bv; ga.bo = bo;
    ga.bn1_g = bn1_g; ga.bn1_b = bn1_b; ga.bn2_g = bn2_g; ga.bn2_b = bn2_b;
    ga.bn3_g = bn3_g; ga.bn3_b = bn3_b;
    ga.mb1 = mb1; ga.mb2 = mb2;
    ga.outf = (float*)d_out;
    ga.bcnt = barp; ga.bgen = barp + 1;

    layers_kernel<<<dim3(GRID), blk, 0, stream>>>(ga);
}

// Round 11
// 414.396 us; speedup vs baseline: 6.7669x; 6.7669x over previous
//
#include <hip/hip_runtime.h>

#define NN 4096
#define NE 65536
#define C 256
#define NL 3
#define NH 8
#define DH 32
#define EPS 1e-5f
#define SPLIT 2              // R30: 4->2. QB=256 keeps per-CU attn block-iters at 16
                             // (iteration law: occupancy-invariant), halves Opart+combine.
#define KT8 (NN/128/SPLIT)   // 128-key tiles per split = 16
#define QB 256               // q rows per attn item
#define VS 136               // V LDS row stride in bf16
#define ATTN_BLKS ((NN/QB)*NH*SPLIT)   // 256

typedef __bf16 bf16x8 __attribute__((ext_vector_type(8)));
typedef __bf16 bf16x4v __attribute__((ext_vector_type(4)));
typedef float f32x4 __attribute__((ext_vector_type(4)));
typedef short bf16x4s __attribute__((ext_vector_type(4)));   // 4 bf16 as i16x4

// scale * log2(e), folded into Q at projection time so softmax uses exp2
#define QSCALE (0.17677669529663687f * 1.4426950408889634f)

#define CC1 (C*C)            // 65536
#define GS 72                // LDS row stride in bf16 (144 B: 2-way alias, free)

// ---------------- weight prep: fp32 -> bf16; qkv stacked per layer ----------------
// Wb layout (units of CC1): gw1 @0 (3), gw2 @3 (3), qkv @6 (9: layer l at 6+3l,
// order q,k,v), wo @15 (3), mw1 @18 (6), mw2 @24 (6). Total 30 CC1.
__global__ __launch_bounds__(256) void prep_w(const float* __restrict__ s0,
        const float* __restrict__ s1, const float* __restrict__ s2,
        const float* __restrict__ s3, const float* __restrict__ s4,
        const float* __restrict__ s5, const float* __restrict__ s6,
        const float* __restrict__ s7, __bf16* __restrict__ dst) {
    int g = blockIdx.y;
    int i = (blockIdx.x*256 + threadIdx.x)*4;
    const float* src; int n;
    switch (g) {
        case 0: src=s0; n=3*CC1; break;
        case 1: src=s1; n=3*CC1; break;
        case 2: src=s2; n=3*CC1; break;
        case 3: src=s3; n=3*CC1; break;
        case 4: src=s4; n=3*CC1; break;
        case 5: src=s5; n=3*CC1; break;
        case 6: src=s6; n=6*CC1; break;
        default: src=s7; n=6*CC1; break;
    }
    if (i >= n) return;
    size_t off;
    if (g >= 2 && g <= 4) {
        int l = i >> 16, rem = i & (CC1-1);
        off = (size_t)(6 + 3*l + (g-2))*CC1 + rem;
    } else {
        size_t base = (g==0) ? 0 : (g==1) ? 3*(size_t)CC1 : (g==5) ? 15*(size_t)CC1
                    : (g==6) ? 18*(size_t)CC1 : 24*(size_t)CC1;
        off = base + i;
    }
    float4 t = *(const float4*)(src + i);
    bf16x4v o = {(__bf16)t.x, (__bf16)t.y, (__bf16)t.z, (__bf16)t.w};
    *(bf16x4v*)(dst + off) = o;
}

// ---------------- lin1 ----------------
__global__ __launch_bounds__(256) void lin1_kernel(const float* __restrict__ x,
        const float* __restrict__ w, const float* __restrict__ b,
        __bf16* __restrict__ out) {
    int n = blockIdx.x, c = threadIdx.x;
    out[(size_t)n*C + c] = (__bf16)(x[n]*w[c] + b[c]);
}

// ---------------- CSR build ----------------
__global__ __launch_bounds__(256) void hist_kernel(const int* __restrict__ ei,
        int* __restrict__ cnt) {
    int e = blockIdx.x*256 + threadIdx.x;
    atomicAdd(&cnt[ei[NE + e]], 1);
}

__global__ __launch_bounds__(256) void scan_kernel(const int* __restrict__ cnt,
        int* __restrict__ rowptr, int* __restrict__ cursor) {
    __shared__ int tot[256];
    __shared__ int pre[257];
    int t = threadIdx.x;
    int base = t*16;
    int local[16];
    int s = 0;
    #pragma unroll
    for (int i = 0; i < 16; i++) { local[i] = s; s += cnt[base+i]; }
    tot[t] = s;
    __syncthreads();
    if (t == 0) {
        int acc = 0;
        for (int i = 0; i < 256; i++) { pre[i] = acc; acc += tot[i]; }
        pre[256] = acc;
    }
    __syncthreads();
    int off = pre[t];
    #pragma unroll
    for (int i = 0; i < 16; i++) {
        rowptr[base+i] = off + local[i];
        cursor[base+i] = off + local[i];
    }
    if (t == 0) rowptr[NN] = pre[256];
}

__global__ __launch_bounds__(256) void fill_kernel(const int* __restrict__ ei,
        int* __restrict__ cursor, int* __restrict__ eidsrc) {
    int e = blockIdx.x*256 + threadIdx.x;
    int dst = ei[NE + e], src = ei[e];
    int pos = atomicAdd(&cursor[dst], 1);
    eidsrc[pos] = src;
}

// ---------------- GEMM core, BK=64, register-prefetch staging ----------------
// R30 additions: AAF template flag = apply per-channel affine (bn3 of the
// previous layer) to the A operand at staging time via LDS coef table
// [sc|sh] (same pattern as ff1's BN==1 fold); rst3/rg3/rb3 = per-column
// affine applied to the add1 residual in the epilogue.
template<int QKV, int BN, int COMB, int AAF>
__device__ __forceinline__ void gemm_core(int bm, int bn,
        const __bf16* A, const float* A2f, const __bf16* A2b, const __bf16* W,
        const float* b0, const float* b1, const float* b2,
        const __bf16* add1, const __bf16* add2,
        __bf16* out, __bf16* vt, __bf16* ktp, float* stats,
        const float* coefs,    // LDS coef table (BN==1)
        const float* st1, const float* g1, const float* bb1,
        const float* st2, const float* g2, const float* bb2,   // BN==2
        const float* lsum,     // COMB
        const float* acoefs,   // LDS [sc|sh] for A-affine (AAF)
        const float* rst3, const float* rg3, const float* rb3, // residual affine
        int K, int Nout, int relu, __bf16* As, __bf16* Ws) {
    int tid = threadIdx.x;
    int wave = tid >> 6, lane = tid & 63;
    int ln = lane & 15, quad = lane >> 4;
    int row = tid >> 2, kseg = (tid & 3) * 16;
    f32x4 acc[4] = {};
    bf16x8 pa0, pa1, pw0, pw1, pz0, pz1;
    float4 pf0, pf1, pf2, pf3;
    bf16x8 pc0[SPLIT], pc1[SPLIT];
    float pwt[SPLIT];
    auto prefetch = [&](int k0) {
        if constexpr (COMB) {
            int rowg = bm + row;
            int head = (k0 + kseg) >> 5;
            #pragma unroll
            for (int zz = 0; zz < SPLIT; zz++) {
                pwt[zz] = lsum[((size_t)zz*NH + head)*NN + rowg];
                const __bf16* p = &A[((size_t)zz*NN + rowg)*C + k0 + kseg];
                pc0[zz] = *(const bf16x8*)p;
                pc1[zz] = *(const bf16x8*)(p + 8);
            }
        } else {
            const __bf16* ap = &A[(size_t)(bm+row)*K + k0 + kseg];
            pa0 = *(const bf16x8*)ap;
            pa1 = *(const bf16x8*)(ap + 8);
            if constexpr (BN == 1) {
                const __bf16* p = &A2b[(size_t)(bm+row)*K + k0 + kseg];
                pz0 = *(const bf16x8*)p;
                pz1 = *(const bf16x8*)(p + 8);
            } else if (A2f) {
                const float* p = &A2f[(size_t)(bm+row)*K + k0 + kseg];
                pf0 = *(const float4*)p;
                pf1 = *(const float4*)(p+4);
                pf2 = *(const float4*)(p+8);
                pf3 = *(const float4*)(p+12);
            }
        }
        const __bf16* wp = &W[(size_t)(bn+row)*K + k0 + kseg];
        pw0 = *(const bf16x8*)wp;
        pw1 = *(const bf16x8*)(wp + 8);
    };
    prefetch(0);
    for (int k0 = 0; k0 < K; k0 += 64) {
        {   // transform prefetched regs and commit to LDS
            bf16x8 a0, a1;
            if constexpr (COMB) {
                float tot = 0.f;
                #pragma unroll
                for (int zz = 0; zz < SPLIT; zz++) tot += pwt[zz];
                float inv = 1.0f / tot;
                float v[16] = {};
                #pragma unroll
                for (int zz = 0; zz < SPLIT; zz++) {
                    #pragma unroll
                    for (int j = 0; j < 8; j++) {
                        v[j]   += pwt[zz]*(float)pc0[zz][j];
                        v[8+j] += pwt[zz]*(float)pc1[zz][j];
                    }
                }
                #pragma unroll
                for (int j = 0; j < 8; j++) {
                    a0[j] = (__bf16)(v[j]*inv);
                    a1[j] = (__bf16)(v[8+j]*inv);
                }
            } else {
                a0 = pa0;
                a1 = pa1;
                if constexpr (AAF) {
                    float asc[16], ash[16];
                    #pragma unroll
                    for (int i = 0; i < 4; i++) {
                        *(float4*)&asc[i*4] = *(const float4*)&acoefs[k0 + kseg + i*4];
                        *(float4*)&ash[i*4] = *(const float4*)&acoefs[C + k0 + kseg + i*4];
                    }
                    #pragma unroll
                    for (int j = 0; j < 8; j++) {
                        a0[j] = (__bf16)((float)a0[j]*asc[j] + ash[j]);
                        a1[j] = (__bf16)((float)a1[j]*asc[8+j] + ash[8+j]);
                    }
                }
                if constexpr (BN == 1) {
                    float sc1[16], sh1[16], sc2[16], sh2[16];
                    #pragma unroll
                    for (int i = 0; i < 4; i++) {
                        *(float4*)&sc1[i*4] = *(const float4*)&coefs[k0 + kseg + i*4];
                        *(float4*)&sh1[i*4] = *(const float4*)&coefs[C + k0 + kseg + i*4];
                        *(float4*)&sc2[i*4] = *(const float4*)&coefs[2*C + k0 + kseg + i*4];
                        *(float4*)&sh2[i*4] = *(const float4*)&coefs[3*C + k0 + kseg + i*4];
                    }
                    #pragma unroll
                    for (int j = 0; j < 8; j++) {
                        a0[j] = (__bf16)((float)a0[j]*sc1[j] + sh1[j]
                                       + (float)pz0[j]*sc2[j] + sh2[j]);
                        a1[j] = (__bf16)((float)a1[j]*sc1[8+j] + sh1[8+j]
                                       + (float)pz1[j]*sc2[8+j] + sh2[8+j]);
                    }
                } else if (A2f) {
                    a0[0]=(__bf16)((float)a0[0]+pf0.x); a0[1]=(__bf16)((float)a0[1]+pf0.y);
                    a0[2]=(__bf16)((float)a0[2]+pf0.z); a0[3]=(__bf16)((float)a0[3]+pf0.w);
                    a0[4]=(__bf16)((float)a0[4]+pf1.x); a0[5]=(__bf16)((float)a0[5]+pf1.y);
                    a0[6]=(__bf16)((float)a0[6]+pf1.z); a0[7]=(__bf16)((float)a0[7]+pf1.w);
                    a1[0]=(__bf16)((float)a1[0]+pf2.x); a1[1]=(__bf16)((float)a1[1]+pf2.y);
                    a1[2]=(__bf16)((float)a1[2]+pf2.z); a1[3]=(__bf16)((float)a1[3]+pf2.w);
                    a1[4]=(__bf16)((float)a1[4]+pf3.x); a1[5]=(__bf16)((float)a1[5]+pf3.y);
                    a1[6]=(__bf16)((float)a1[6]+pf3.z); a1[7]=(__bf16)((float)a1[7]+pf3.w);
                }
            }
            *(bf16x8*)&As[row*GS + kseg]     = a0;
            *(bf16x8*)&As[row*GS + kseg + 8] = a1;
            *(bf16x8*)&Ws[row*GS + kseg]     = pw0;
            *(bf16x8*)&Ws[row*GS + kseg + 8] = pw1;
        }
        __syncthreads();
        if (k0 + 64 < K) prefetch(k0 + 64);   // VMEM issues overlap MFMA below
        #pragma unroll
        for (int kt2 = 0; kt2 < 2; kt2++) {
            bf16x8 bfr = *(const bf16x8*)&Ws[(wave*16+ln)*GS + kt2*32 + quad*8];
            #pragma unroll
            for (int i = 0; i < 4; i++) {
                bf16x8 afr = *(const bf16x8*)&As[(i*16+ln)*GS + kt2*32 + quad*8];
                acc[i] = __builtin_amdgcn_mfma_f32_16x16x32_bf16(afr, bfr, acc[i], 0, 0, 0);
            }
        }
        __syncthreads();                      // LDS reads done before next write
    }
    int col = bn + wave*16 + ln;
    if constexpr (QKV) {
        float bsv = col < 256 ? b0[col] : (col < 512 ? b1[col-256] : b2[col-512]);
        if (col < 256) {
            #pragma unroll
            for (int i = 0; i < 4; i++)
                #pragma unroll
                for (int rr = 0; rr < 4; rr++)
                    out[(size_t)(bm + i*16 + quad*4 + rr)*C + col] =
                        (__bf16)((acc[i][rr] + bsv) * (float)QSCALE);
        } else if (col < 512) {
            int hd = (col-256) >> 5, dh = (col-256) & 31;
            #pragma unroll
            for (int i = 0; i < 4; i++)
                #pragma unroll
                for (int rr = 0; rr < 4; rr++)
                    ktp[((size_t)hd*NN + bm + i*16 + quad*4 + rr)*DH + dh] =
                        (__bf16)(acc[i][rr] + bsv);
        } else {
            int vrow = col - 512;
            #pragma unroll
            for (int i = 0; i < 4; i++) {
                bf16x4v pk = {(__bf16)(acc[i][0]+bsv), (__bf16)(acc[i][1]+bsv),
                              (__bf16)(acc[i][2]+bsv), (__bf16)(acc[i][3]+bsv)};
                *(bf16x4v*)&vt[(size_t)vrow*NN + bm + i*16 + quad*4] = pk;
            }
        }
        return;
    }
    float bsv = b0[col];
    float sc1 = 0.f, sh1 = 0.f, sc2 = 0.f, sh2 = 0.f;
    if constexpr (BN == 2) {
        float m1 = st1[col]*(1.f/NN);
        sc1 = rsqrtf(st1[C+col]*(1.f/NN) - m1*m1 + EPS) * g1[col];
        sh1 = bb1[col] - m1*sc1;
        float m2 = st2[col]*(1.f/NN);
        sc2 = rsqrtf(st2[C+col]*(1.f/NN) - m2*m2 + EPS) * g2[col];
        sh2 = bb2[col] - m2*sc2;
    }
    float r1sc = 1.f, r1sh = 0.f;
    if (rst3) {   // residual add1 is raw zbuf3 -> apply prev-layer bn3 per col
        float m3 = rst3[col]*(1.f/NN);
        r1sc = rsqrtf(rst3[C+col]*(1.f/NN) - m3*m3 + EPS) * rg3[col];
        r1sh = rb3[col] - m3*r1sc;
    }
    float ssum = 0.f, ssq = 0.f;
    #pragma unroll
    for (int i = 0; i < 4; i++) {
        #pragma unroll
        for (int rr = 0; rr < 4; rr++) {
            int rw = bm + i*16 + quad*4 + rr;
            float vv = acc[i][rr] + bsv;
            if (relu) vv = fmaxf(vv, 0.f);
            size_t idx = (size_t)rw*Nout + col;
            if constexpr (BN == 2) {
                vv += (float)add1[idx]*sc1 + sh1 + (float)add2[idx]*sc2 + sh2;
            } else {
                if (add1) {
                    float t1v = (float)add1[idx];
                    vv += rst3 ? (t1v*r1sc + r1sh) : t1v;
                }
                if (add2) vv += (float)add2[idx];
            }
            out[idx] = (__bf16)vv;
            ssum += vv; ssq += vv*vv;
        }
    }
    if (stats) {
        ssum += __shfl_xor(ssum, 16); ssum += __shfl_xor(ssum, 32);
        ssq  += __shfl_xor(ssq, 16);  ssq  += __shfl_xor(ssq, 32);
        if (quad == 0) {
            atomicAdd(&stats[col], ssum);
            atomicAdd(&stats[Nout + col], ssq);
        }
    }
}

// ---------------- attention body: 256-q tiles, SPLIT=2 ----------------
__device__ __forceinline__ void attn_body(int t, const __bf16* __restrict__ qbuf,
        const __bf16* __restrict__ kt, const __bf16* __restrict__ vt,
        __bf16* __restrict__ opart, float* __restrict__ lsum, __bf16* lds) {
    int head = t & 7, qi = (t >> 3) & 15, z = t >> 7;
    int qb = qi * QB;
    int hb = head * DH;
    int tid = threadIdx.x;
    int wave = tid >> 6, lane = tid & 63;
    int ln = lane & 15, quad = lane >> 4;
    __bf16* Kb0 = lds;                    // [128][36] = 4608 elems each
    __bf16* Kb1 = lds + 4608;
    __bf16* Vb0 = lds + 9216;             // [32][VS] = 4352 elems each
    __bf16* Vb1 = lds + 9216 + 32*VS;

    bf16x8 qf[4];
    #pragma unroll
    for (int g = 0; g < 4; g++)
        qf[g] = *(const bf16x8*)&qbuf[(size_t)(qb + wave*64 + g*16 + ln)*C + hb + quad*8];

    f32x4 ot[4][2] = {};
    f32x4 la[4] = {};
    const bf16x4s ones = {(short)0x3F80, (short)0x3F80, (short)0x3F80, (short)0x3F80};
    const f32x4 zz = {0.f,0.f,0.f,0.f};

    int srow = tid >> 1, sseg = (tid & 1) * 16;   // K staging: 2 threads/row (64B rows)
    int vd = tid >> 3, vseg = (tid & 7) * 16;     // V staging: 8 threads/dim-row
    int kt0 = z * KT8;
    const __bf16* kbase = &kt[(size_t)head*NN*DH];
    {   // prologue: stage tile (rotated start decorrelates VMEM bursts)
        int i0 = qi & (KT8-1);
        const __bf16* kp = &kbase[(size_t)((kt0+i0)*128 + srow)*DH + sseg];
        *(bf16x8*)&Kb0[srow*36 + sseg]     = *(const bf16x8*)kp;
        *(bf16x8*)&Kb0[srow*36 + sseg + 8] = *(const bf16x8*)(kp + 8);
        const __bf16* vp = &vt[(size_t)(hb + vd)*NN + (kt0+i0)*128 + vseg];
        *(bf16x8*)&Vb0[vd*VS + vseg]     = *(const bf16x8*)vp;
        *(bf16x8*)&Vb0[vd*VS + vseg + 8] = *(const bf16x8*)(vp + 8);
    }
    for (int ii = 0; ii < KT8; ii++) {
        int inext = (ii + 1 + qi) & (KT8-1);
        __bf16* Kc = (ii & 1) ? Kb1 : Kb0;
        __bf16* Kn = (ii & 1) ? Kb0 : Kb1;
        __bf16* Vc = (ii & 1) ? Vb1 : Vb0;
        __bf16* Vn = (ii & 1) ? Vb0 : Vb1;
        __syncthreads();                       // Kc/Vc writes visible
        bf16x8 nk0, nk1, nv0, nv1;
        bool hasNext = (ii + 1 < KT8);
        if (hasNext) {                          // next-tile loads overlap compute
            const __bf16* kp = &kbase[(size_t)((kt0+inext)*128 + srow)*DH + sseg];
            nk0 = *(const bf16x8*)kp;
            nk1 = *(const bf16x8*)(kp + 8);
            const __bf16* vp = &vt[(size_t)(hb + vd)*NN + (kt0+inext)*128 + vseg];
            nv0 = *(const bf16x8*)vp;
            nv1 = *(const bf16x8*)(vp + 8);
        }
        #pragma unroll
        for (int pr = 0; pr < 4; pr++) {
            #pragma unroll
            for (int s = 0; s < 2; s++) {
                int ks = pr*2 + s;
                bf16x8 kf = *(const bf16x8*)&Kc[(ks*16+ln)*36 + quad*8];
                bf16x4s vf0 = *(const bf16x4s*)&Vc[(0*16+ln)*VS + ks*16 + quad*4];
                bf16x4s vf1 = *(const bf16x4s*)&Vc[(1*16+ln)*VS + ks*16 + quad*4];
                f32x4 st0 = __builtin_amdgcn_mfma_f32_16x16x32_bf16(kf, qf[0], zz, 0, 0, 0);
                f32x4 st1 = __builtin_amdgcn_mfma_f32_16x16x32_bf16(kf, qf[1], zz, 0, 0, 0);
                f32x4 st2 = __builtin_amdgcn_mfma_f32_16x16x32_bf16(kf, qf[2], zz, 0, 0, 0);
                f32x4 st3 = __builtin_amdgcn_mfma_f32_16x16x32_bf16(kf, qf[3], zz, 0, 0, 0);
                union { __bf16 b[4]; bf16x4s s; } pf0, pf1, pf2, pf3;
                #pragma unroll
                for (int rr = 0; rr < 4; rr++) {
                    pf0.b[rr] = (__bf16)__builtin_amdgcn_exp2f(st0[rr]);
                    pf1.b[rr] = (__bf16)__builtin_amdgcn_exp2f(st1[rr]);
                    pf2.b[rr] = (__bf16)__builtin_amdgcn_exp2f(st2[rr]);
                    pf3.b[rr] = (__bf16)__builtin_amdgcn_exp2f(st3[rr]);
                }
                ot[0][0] = __builtin_amdgcn_mfma_f32_16x16x16bf16_1k(vf0, pf0.s, ot[0][0], 0, 0, 0);
                ot[0][1] = __builtin_amdgcn_mfma_f32_16x16x16bf16_1k(vf1, pf0.s, ot[0][1], 0, 0, 0);
                ot[1][0] = __builtin_amdgcn_mfma_f32_16x16x16bf16_1k(vf0, pf1.s, ot[1][0], 0, 0, 0);
                ot[1][1] = __builtin_amdgcn_mfma_f32_16x16x16bf16_1k(vf1, pf1.s, ot[1][1], 0, 0, 0);
                ot[2][0] = __builtin_amdgcn_mfma_f32_16x16x16bf16_1k(vf0, pf2.s, ot[2][0], 0, 0, 0);
                ot[2][1] = __builtin_amdgcn_mfma_f32_16x16x16bf16_1k(vf1, pf2.s, ot[2][1], 0, 0, 0);
                ot[3][0] = __builtin_amdgcn_mfma_f32_16x16x16bf16_1k(vf0, pf3.s, ot[3][0], 0, 0, 0);
                ot[3][1] = __builtin_amdgcn_mfma_f32_16x16x16bf16_1k(vf1, pf3.s, ot[3][1], 0, 0, 0);
                la[0]    = __builtin_amdgcn_mfma_f32_16x16x16bf16_1k(ones, pf0.s, la[0], 0, 0, 0);
                la[1]    = __builtin_amdgcn_mfma_f32_16x16x16bf16_1k(ones, pf1.s, la[1], 0, 0, 0);
                la[2]    = __builtin_amdgcn_mfma_f32_16x16x16bf16_1k(ones, pf2.s, la[2], 0, 0, 0);
                la[3]    = __builtin_amdgcn_mfma_f32_16x16x16bf16_1k(ones, pf3.s, la[3], 0, 0, 0);
            }
        }
        if (hasNext) {
            *(bf16x8*)&Kn[srow*36 + sseg]     = nk0;
            *(bf16x8*)&Kn[srow*36 + sseg + 8] = nk1;
            *(bf16x8*)&Vn[vd*VS + vseg]     = nv0;
            *(bf16x8*)&Vn[vd*VS + vseg + 8] = nv1;
        }
    }
    #pragma unroll
    for (int g = 0; g < 4; g++) {
        float l_ = la[g][0];
        float inv = 1.0f / l_;
        int qrow = qb + wave*64 + g*16 + ln;
        #pragma unroll
        for (int h = 0; h < 2; h++) {
            bf16x4v pk = {(__bf16)(ot[g][h][0]*inv), (__bf16)(ot[g][h][1]*inv),
                          (__bf16)(ot[g][h][2]*inv), (__bf16)(ot[g][h][3]*inv)};
            *(bf16x4v*)&opart[((size_t)z*NN + qrow)*C + hb + h*16 + quad*4] = pk;
        }
        if (quad == 0)
            lsum[((size_t)z*NH + head)*NN + qrow] = l_;
    }
}

// ---------------- kernel 1: QKV gemm + CSR gather agg (bn3 fold on srcH) ----------
__global__ __launch_bounds__(256) void qkv_agg_kernel(const __bf16* __restrict__ srcH,
        const __bf16* __restrict__ Wqkv, const float* __restrict__ bq,
        const float* __restrict__ bk, const float* __restrict__ bv,
        __bf16* __restrict__ qout, __bf16* __restrict__ ktout,
        __bf16* __restrict__ vtout,
        const int* __restrict__ rowptr, const int* __restrict__ eidsrc,
        float* __restrict__ agg,
        const float* __restrict__ st3p, const float* __restrict__ g3p,
        const float* __restrict__ b3p) {
    __shared__ __bf16 lds[9216];
    __shared__ float coefs[2*C];
    int tid = threadIdx.x;
    if (st3p) {
        float m = st3p[tid]*(1.f/NN);
        float sc = rsqrtf(st3p[C+tid]*(1.f/NN) - m*m + EPS) * g3p[tid];
        coefs[tid] = sc; coefs[C+tid] = b3p[tid] - m*sc;
    } else { coefs[tid] = 1.f; coefs[C+tid] = 0.f; }
    __syncthreads();
    int bx = blockIdx.x;
    if (bx < 768) {
        gemm_core<1,0,0,1>((bx & 63)*64, (bx >> 6)*64, srcH, nullptr, nullptr, Wqkv,
                bq, bk, bv, nullptr, nullptr, qout, vtout, ktout, nullptr,
                nullptr, nullptr, nullptr, nullptr, nullptr, nullptr, nullptr,
                nullptr, coefs, nullptr, nullptr, nullptr,
                C, 768, 0, lds, lds + 4608);
        return;
    }
    int wave = tid >> 6, lane = tid & 63;
    float4 sc4 = *(const float4*)&coefs[lane*4];
    float4 sh4 = *(const float4*)&coefs[C + lane*4];
    int node = (bx - 768)*4 + wave;
    int beg = rowptr[node], end = rowptr[node+1];
    float s0 = 0.f, s1 = 0.f, s2 = 0.f, s3 = 0.f;
    for (int e = beg; e < end; e++) {
        int src = eidsrc[e];
        bf16x4v hv = *(const bf16x4v*)&srcH[(size_t)src*C + lane*4];
        s0 += sc4.x*(float)hv[0] + sh4.x;
        s1 += sc4.y*(float)hv[1] + sh4.y;
        s2 += sc4.z*(float)hv[2] + sh4.z;
        s3 += sc4.w*(float)hv[3] + sh4.w;
    }
    float4 o = {s0, s1, s2, s3};
    *(float4*)&agg[(size_t)node*C + lane*4] = o;
}

// ---------------- kernel 2: GIN gemm1 (first, drains early) + attention ----------------
__global__ __launch_bounds__(256, 2) void gin1_attn_kernel(const __bf16* __restrict__ srcH,
        const float* __restrict__ agg, const __bf16* __restrict__ gw1,
        const float* __restrict__ gb1, __bf16* __restrict__ t1,
        const __bf16* __restrict__ qbuf, const __bf16* __restrict__ kt,
        const __bf16* __restrict__ vt,
        __bf16* __restrict__ opart, float* __restrict__ lsum,
        const float* __restrict__ st3p, const float* __restrict__ g3p,
        const float* __restrict__ b3p) {
    __shared__ __bf16 lds[17920];     // attn 17920; gemm uses first 9216
    __shared__ float coefs[2*C];
    int tid = threadIdx.x;
    if (st3p) {
        float m = st3p[tid]*(1.f/NN);
        float sc = rsqrtf(st3p[C+tid]*(1.f/NN) - m*m + EPS) * g3p[tid];
        coefs[tid] = sc; coefs[C+tid] = b3p[tid] - m*sc;
    } else { coefs[tid] = 1.f; coefs[C+tid] = 0.f; }
    __syncthreads();
    int bx = blockIdx.x;
    if (bx < 256) {
        gemm_core<0,0,0,1>((bx >> 2)*64, (bx & 3)*64, srcH, agg, nullptr, gw1,
                gb1, nullptr, nullptr, nullptr, nullptr, t1, nullptr, nullptr,
                nullptr, nullptr, nullptr, nullptr, nullptr, nullptr, nullptr,
                nullptr, nullptr, coefs, nullptr, nullptr, nullptr,
                C, C, 1, lds, lds + 4608);
        return;
    }
    attn_body(bx - 256, qbuf, kt, vt, opart, lsum, lds);
}

// ---------------- kernel 3: GIN gemm2 + proj-with-combine (bn3 fold on residual) ------
__global__ __launch_bounds__(256) void gin2_proj_kernel(const __bf16* __restrict__ t1,
        const __bf16* __restrict__ gw2, const float* __restrict__ gb2,
        const __bf16* __restrict__ srcH, __bf16* __restrict__ z1, float* __restrict__ st1,
        const __bf16* __restrict__ opart, const float* __restrict__ lsum,
        const __bf16* __restrict__ wop, const float* __restrict__ lbo,
        __bf16* __restrict__ z2, float* __restrict__ st2,
        const float* __restrict__ st3p, const float* __restrict__ g3p,
        const float* __restrict__ b3p) {
    __shared__ __bf16 lds[9216];
    int bx = blockIdx.x;
    if (bx < 256) {
        gemm_core<0,0,0,0>((bx >> 2)*64, (bx & 3)*64, t1, nullptr, nullptr, gw2,
                gb2, nullptr, nullptr, srcH, nullptr, z1, nullptr, nullptr, st1,
                nullptr, nullptr, nullptr, nullptr, nullptr, nullptr, nullptr,
                nullptr, nullptr, st3p, g3p, b3p,
                C, C, 0, lds, lds + 4608);
        return;
    }
    int t = bx - 256;
    gemm_core<0,0,1,0>((t >> 2)*64, (t & 3)*64, opart, nullptr, nullptr, wop,
            lbo, nullptr, nullptr, srcH, nullptr, z2, nullptr, nullptr, st2,
            nullptr, nullptr, nullptr, nullptr, nullptr, nullptr, nullptr,
            lsum, nullptr, st3p, g3p, b3p,
            C, C, 0, lds, lds + 4608);
}

// ---------------- kernel 4: ff1 with inline bn1/bn2 on staging ----------------
__global__ __launch_bounds__(256) void ff1_kernel(const __bf16* __restrict__ z1,
        const __bf16* __restrict__ z2, const __bf16* __restrict__ mw1,
        const float* __restrict__ lmb1, __bf16* __restrict__ hidden,
        const float* __restrict__ st1, const float* __restrict__ g1,
        const float* __restrict__ bb1, const float* __restrict__ st2,
        const float* __restrict__ g2, const float* __restrict__ bb2) {
    __shared__ __bf16 lds[9216];
    __shared__ float coefs[4*C];
    int tid = threadIdx.x;
    {   // fold BN stats -> (scale, shift) per channel, in LDS
        float m = st1[tid]*(1.f/NN);
        float var = st1[C+tid]*(1.f/NN) - m*m;
        float s = rsqrtf(var + EPS) * g1[tid];
        coefs[tid] = s; coefs[C+tid] = bb1[tid] - m*s;
        m = st2[tid]*(1.f/NN);
        var = st2[C+tid]*(1.f/NN) - m*m;
        s = rsqrtf(var + EPS) * g2[tid];
        coefs[2*C+tid] = s; coefs[3*C+tid] = bb2[tid] - m*s;
    }
    __syncthreads();   // staging reads coefs before gemm_core's first barrier
    int bx = blockIdx.x;
    gemm_core<0,1,0,0>((bx >> 3)*64, (bx & 7)*64, z1, nullptr, z2, mw1,
            lmb1, nullptr, nullptr, nullptr, nullptr, hidden, nullptr, nullptr,
            nullptr, coefs, nullptr, nullptr, nullptr, nullptr, nullptr, nullptr,
            nullptr, nullptr, nullptr, nullptr, nullptr,
            C, 2*C, 1, lds, lds + 4608);
}

// ---------------- kernel 5: ff2 with inline bn residuals in epilogue ----------------
__global__ __launch_bounds__(256) void ff2_kernel(const __bf16* __restrict__ hidden,
        const __bf16* __restrict__ mw2, const float* __restrict__ lmb2,
        const __bf16* __restrict__ z1, const __bf16* __restrict__ z2,
        __bf16* __restrict__ zbuf3, float* __restrict__ st3,
        const float* __restrict__ st1, const float* __restrict__ g1,
        const float* __restrict__ bb1, const float* __restrict__ st2,
        const float* __restrict__ g2, const float* __restrict__ bb2) {
    __shared__ __bf16 lds[9216];
    int bx = blockIdx.x;
    gemm_core<0,2,0,0>((bx >> 2)*64, (bx & 3)*64, hidden, nullptr, nullptr, mw2,
            lmb2, nullptr, nullptr, z1, z2, zbuf3, nullptr, nullptr, st3,
            nullptr, st1, g1, bb1, st2, g2, bb2,
            nullptr, nullptr, nullptr, nullptr, nullptr,
            2*C, C, 0, lds, lds + 4608);
}

// ---------------- BatchNorm apply (final layer only) ----------------
__global__ __launch_bounds__(256) void bn_apply_kernel(const __bf16* __restrict__ z,
        const float* __restrict__ stats, const float* __restrict__ g,
        const float* __restrict__ b, float* __restrict__ outf) {
    int idx4 = (blockIdx.x*256 + threadIdx.x) * 4;
    int c = idx4 & (C-1);
    bf16x4v zv = *(const bf16x4v*)&z[idx4];
    float4 st = *(const float4*)&stats[c];
    float4 sq = *(const float4*)&stats[C + c];
    float4 gv = *(const float4*)&g[c];
    float4 bv = *(const float4*)&b[c];
    float o[4];
    float m0 = st.x*(1.f/NN), m1 = st.y*(1.f/NN), m2 = st.z*(1.f/NN), m3 = st.w*(1.f/NN);
    o[0] = ((float)zv[0] - m0) * rsqrtf(sq.x*(1.f/NN) - m0*m0 + EPS) * gv.x + bv.x;
    o[1] = ((float)zv[1] - m1) * rsqrtf(sq.y*(1.f/NN) - m1*m1 + EPS) * gv.y + bv.y;
    o[2] = ((float)zv[2] - m2) * rsqrtf(sq.z*(1.f/NN) - m2*m2 + EPS) * gv.z + bv.z;
    o[3] = ((float)zv[3] - m3) * rsqrtf(sq.w*(1.f/NN) - m3*m3 + EPS) * gv.w + bv.w;
    float4 ov = {o[0], o[1], o[2], o[3]};
    *(float4*)&outf[idx4] = ov;
}

extern "C" void kernel_launch(void* const* d_in, const int* in_sizes, int n_in,
                              void* d_out, int out_size, void* d_ws, size_t ws_size,
                              hipStream_t stream) {
    const float* x      = (const float*)d_in[0];
    const int*   ei     = (const int*)d_in[1];
    const float* lin1_w = (const float*)d_in[2];
    const float* lin1_b = (const float*)d_in[3];
    const float* gin_w1 = (const float*)d_in[4];
    const float* gin_b1 = (const float*)d_in[5];
    const float* gin_w2 = (const float*)d_in[6];
    const float* gin_b2 = (const float*)d_in[7];
    const float* wq = (const float*)d_in[8];
    const float* wk = (const float*)d_in[9];
    const float* wv = (const float*)d_in[10];
    const float* wo = (const float*)d_in[11];
    const float* bq = (const float*)d_in[12];
    const float* bk = (const float*)d_in[13];
    const float* bv = (const float*)d_in[14];
    const float* bo = (const float*)d_in[15];
    const float* bn1_g = (const float*)d_in[16];
    const float* bn1_b = (const float*)d_in[17];
    const float* bn2_g = (const float*)d_in[18];
    const float* bn2_b = (const float*)d_in[19];
    const float* bn3_g = (const float*)d_in[20];
    const float* bn3_b = (const float*)d_in[21];
    const float* mw1 = (const float*)d_in[22];
    const float* mb1 = (const float*)d_in[23];
    const float* mw2 = (const float*)d_in[24];
    const float* mb2 = (const float*)d_in[25];

    const size_t MB = 1u << 20;
    char* ws = (char*)d_ws;
    __bf16* Hb      = (__bf16*)(ws);            // 2 MB  layer-0 input (lin1 output)
    __bf16* z1      = (__bf16*)(ws + 2*MB);     // 2 MB  GIN pre-bn1
    __bf16* zbuf3   = (__bf16*)(ws + 4*MB);     // 2 MB  raw pre-bn3 (consumed with fold)
    __bf16* z2      = (__bf16*)(ws + 6*MB);     // 2 MB  attn pre-bn2
    __bf16* t1      = (__bf16*)(ws + 8*MB);     // 2 MB  GIN hidden
    __bf16* Qbuf    = (__bf16*)(ws + 10*MB);    // 2 MB  [N][C] (QSCALE folded)
    __bf16* Ktb     = (__bf16*)(ws + 12*MB);    // 2 MB  [NH][NN][DH] head-major K
    __bf16* Vt      = (__bf16*)(ws + 14*MB);    // 2 MB  [C][N]
    float*  agg     = (float*)(ws + 16*MB);     // 4 MB  (dead after gin1)
    __bf16* hiddenb = (__bf16*)(ws + 16*MB);    // 4 MB  shares agg region (agg dead
                                                //       after gin1; hidden lives k4->k5)
    __bf16* Opart   = (__bf16*)(ws + 20*MB);    // 4 MB  (SPLIT=2)
    __bf16* Wb      = (__bf16*)(ws + 28*MB);    // 3.93 MB
    float*  stats   = (float*)(ws + 32*MB);     // 9 x 2C
    int*    cursor  = (int*)(ws + 32*MB + 64*1024);
    int*    rowptr  = (int*)(ws + 32*MB + 96*1024);
    int*    eidsrc  = (int*)(ws + 32*MB + 128*1024);
    float*  lsum    = (float*)(ws + 33*MB);     // 0.25 MB (SPLIT=2), dedicated

    dim3 blk(256);

    prep_w<<<dim3(384, 8), blk, 0, stream>>>(gin_w1, gin_w2, wq, wk, wv, wo, mw1, mw2, Wb);
    hipMemsetAsync(stats, 0, 9 * 2 * C * sizeof(float), stream);
    lin1_kernel<<<NN, blk, 0, stream>>>(x, lin1_w, lin1_b, Hb);
    hipMemsetAsync(cursor, 0, NN * sizeof(int), stream);
    hist_kernel<<<NE/256, blk, 0, stream>>>(ei, cursor);
    scan_kernel<<<1, blk, 0, stream>>>(cursor, rowptr, cursor);
    fill_kernel<<<NE/256, blk, 0, stream>>>(ei, cursor, eidsrc);

    for (int l = 0; l < NL; l++) {
        const __bf16* gw1b = Wb + (size_t)l*CC1;
        const __bf16* gw2b = Wb + (size_t)(3+l)*CC1;
        const __bf16* wqkv = Wb + (size_t)(6+3*l)*CC1;
        const __bf16* wop  = Wb + (size_t)(15+l)*CC1;
        const __bf16* mw1p = Wb + (size_t)(18+2*l)*CC1;
        const __bf16* mw2p = Wb + (size_t)(24+2*l)*CC1;
        const float* gb1 = gin_b1 + (size_t)l*C;
        const float* gb2 = gin_b2 + (size_t)l*C;
        const float* lbq = bq + (size_t)l*C;
        const float* lbk = bk + (size_t)l*C;
        const float* lbv = bv + (size_t)l*C;
        const float* lbo = bo + (size_t)l*C;
        const float* lmb1 = mb1 + (size_t)l*2*C;
        const float* lmb2 = mb2 + (size_t)l*C;
        float* st1 = stats + (size_t)l*3*2*C;
        float* st2 = st1 + 2*C;
        float* st3 = st2 + 2*C;
        const float* g1v = bn1_g + (size_t)l*C; const float* b1v = bn1_b + (size_t)l*C;
        const float* g2v = bn2_g + (size_t)l*C; const float* b2v = bn2_b + (size_t)l*C;

        // bn3 fold: layer l>=1 consumes raw zbuf3 + prev layer's bn3 affine
        const __bf16* srcH = (l == 0) ? Hb : zbuf3;
        const float* st3p = (l == 0) ? nullptr : stats + (size_t)(l-1)*3*2*C + 4*C;
        const float* g3p  = (l == 0) ? nullptr : bn3_g + (size_t)(l-1)*C;
        const float* b3p  = (l == 0) ? nullptr : bn3_b + (size_t)(l-1)*C;

        // 1. stacked-QKV projection (Q / head-major K / V^T) + gather aggregation
        qkv_agg_kernel<<<768 + NN/4, blk, 0, stream>>>(srcH, wqkv, lbq, lbk, lbv,
                Qbuf, Ktb, Vt, rowptr, eidsrc, agg, st3p, g3p, b3p);
        // 2. GIN gemm1 (first, drains early) + flash attention (256-q, SPLIT=2)
        gin1_attn_kernel<<<256 + ATTN_BLKS, blk, 0, stream>>>(srcH, agg,
                gw1b, gb1, t1, Qbuf, Ktb, Vt, Opart, lsum, st3p, g3p, b3p);
        // 3. GIN gemm2 + proj-with-inline-combine (residual = bn3(zbuf3))
        gin2_proj_kernel<<<512, blk, 0, stream>>>(t1, gw2b, gb2, srcH, z1, st1,
                Opart, lsum, wop, lbo, z2, st2, st3p, g3p, b3p);
        // 4. ff1: bn1(z1)+bn2(z2) folded into staging
        ff1_kernel<<<512, blk, 0, stream>>>(z1, z2, mw1p, lmb1, hiddenb,
                st1, g1v, b1v, st2, g2v, b2v);
        // 5. ff2: bn residuals in epilogue, writes raw zbuf3
        ff2_kernel<<<256, blk, 0, stream>>>(hiddenb, mw2p, lmb2, z1, z2,
                zbuf3, st3, st1, g1v, b1v, st2, g2v, b2v);
        // 6. bn3 apply only for the final layer (f32 output)
        if (l == NL-1)
            bn_apply_kernel<<<NN/4, blk, 0, stream>>>(zbuf3, st3,
                    bn3_g + (size_t)l*C, bn3_b + (size_t)l*C, (float*)d_out);
    }
}

// Round 12
// 394.024 us; speedup vs baseline: 7.1168x; 1.0517x over previous
//
#include <hip/hip_runtime.h>

#define NN 4096
#define NE 65536
#define C 256
#define NL 3
#define NH 8
#define DH 32
#define EPS 1e-5f
#define SPLIT 4              // R31: restore 4 (R25 measured-best attn: 512 blocks,
                             // 2/CU, 8 iters, ~43us). R30's SPLIT=2 put attn at
                             // 1 block/CU -> +7us/dispatch (iteration law needs >=2/CU).
#define KT8 (NN/128/SPLIT)   // 128-key tiles per split = 8
#define QB 256               // q rows per attn item
#define VS 136               // V LDS row stride in bf16
#define ATTN_BLKS ((NN/QB)*NH*SPLIT)   // 512

typedef __bf16 bf16x8 __attribute__((ext_vector_type(8)));
typedef __bf16 bf16x4v __attribute__((ext_vector_type(4)));
typedef float f32x4 __attribute__((ext_vector_type(4)));
typedef short bf16x4s __attribute__((ext_vector_type(4)));   // 4 bf16 as i16x4

// scale * log2(e), folded into Q at projection time so softmax uses exp2
#define QSCALE (0.17677669529663687f * 1.4426950408889634f)

#define CC1 (C*C)            // 65536
#define GS 72                // LDS row stride in bf16 (144 B: 2-way alias, free)

// ---------------- weight prep: fp32 -> bf16; qkv stacked per layer ----------------
// Wb layout (units of CC1): gw1 @0 (3), gw2 @3 (3), qkv @6 (9: layer l at 6+3l,
// order q,k,v), wo @15 (3), mw1 @18 (6), mw2 @24 (6). Total 30 CC1.
__global__ __launch_bounds__(256) void prep_w(const float* __restrict__ s0,
        const float* __restrict__ s1, const float* __restrict__ s2,
        const float* __restrict__ s3, const float* __restrict__ s4,
        const float* __restrict__ s5, const float* __restrict__ s6,
        const float* __restrict__ s7, __bf16* __restrict__ dst) {
    int g = blockIdx.y;
    int i = (blockIdx.x*256 + threadIdx.x)*4;
    const float* src; int n;
    switch (g) {
        case 0: src=s0; n=3*CC1; break;
        case 1: src=s1; n=3*CC1; break;
        case 2: src=s2; n=3*CC1; break;
        case 3: src=s3; n=3*CC1; break;
        case 4: src=s4; n=3*CC1; break;
        case 5: src=s5; n=3*CC1; break;
        case 6: src=s6; n=6*CC1; break;
        default: src=s7; n=6*CC1; break;
    }
    if (i >= n) return;
    size_t off;
    if (g >= 2 && g <= 4) {
        int l = i >> 16, rem = i & (CC1-1);
        off = (size_t)(6 + 3*l + (g-2))*CC1 + rem;
    } else {
        size_t base = (g==0) ? 0 : (g==1) ? 3*(size_t)CC1 : (g==5) ? 15*(size_t)CC1
                    : (g==6) ? 18*(size_t)CC1 : 24*(size_t)CC1;
        off = base + i;
    }
    float4 t = *(const float4*)(src + i);
    bf16x4v o = {(__bf16)t.x, (__bf16)t.y, (__bf16)t.z, (__bf16)t.w};
    *(bf16x4v*)(dst + off) = o;
}

// ---------------- lin1 ----------------
__global__ __launch_bounds__(256) void lin1_kernel(const float* __restrict__ x,
        const float* __restrict__ w, const float* __restrict__ b,
        __bf16* __restrict__ out) {
    int n = blockIdx.x, c = threadIdx.x;
    out[(size_t)n*C + c] = (__bf16)(x[n]*w[c] + b[c]);
}

// ---------------- CSR build ----------------
__global__ __launch_bounds__(256) void hist_kernel(const int* __restrict__ ei,
        int* __restrict__ cnt) {
    int e = blockIdx.x*256 + threadIdx.x;
    atomicAdd(&cnt[ei[NE + e]], 1);
}

__global__ __launch_bounds__(256) void scan_kernel(const int* __restrict__ cnt,
        int* __restrict__ rowptr, int* __restrict__ cursor) {
    __shared__ int tot[256];
    __shared__ int pre[257];
    int t = threadIdx.x;
    int base = t*16;
    int local[16];
    int s = 0;
    #pragma unroll
    for (int i = 0; i < 16; i++) { local[i] = s; s += cnt[base+i]; }
    tot[t] = s;
    __syncthreads();
    if (t == 0) {
        int acc = 0;
        for (int i = 0; i < 256; i++) { pre[i] = acc; acc += tot[i]; }
        pre[256] = acc;
    }
    __syncthreads();
    int off = pre[t];
    #pragma unroll
    for (int i = 0; i < 16; i++) {
        rowptr[base+i] = off + local[i];
        cursor[base+i] = off + local[i];
    }
    if (t == 0) rowptr[NN] = pre[256];
}

__global__ __launch_bounds__(256) void fill_kernel(const int* __restrict__ ei,
        int* __restrict__ cursor, int* __restrict__ eidsrc) {
    int e = blockIdx.x*256 + threadIdx.x;
    int dst = ei[NE + e], src = ei[e];
    int pos = atomicAdd(&cursor[dst], 1);
    eidsrc[pos] = src;
}

// ---------------- GEMM core, BK=64, register-prefetch staging ----------------
// AAF template flag = apply per-channel affine (prev layer's bn3) to the A
// operand at staging time via LDS coef table [sc|sh]; rst3/rg3/rb3 = per-column
// affine applied to the add1 residual in the epilogue.
template<int QKV, int BN, int COMB, int AAF>
__device__ __forceinline__ void gemm_core(int bm, int bn,
        const __bf16* A, const float* A2f, const __bf16* A2b, const __bf16* W,
        const float* b0, const float* b1, const float* b2,
        const __bf16* add1, const __bf16* add2,
        __bf16* out, __bf16* vt, __bf16* ktp, float* stats,
        const float* coefs,    // LDS coef table (BN==1)
        const float* st1, const float* g1, const float* bb1,
        const float* st2, const float* g2, const float* bb2,   // BN==2
        const float* lsum,     // COMB
        const float* acoefs,   // LDS [sc|sh] for A-affine (AAF)
        const float* rst3, const float* rg3, const float* rb3, // residual affine
        int K, int Nout, int relu, __bf16* As, __bf16* Ws) {
    int tid = threadIdx.x;
    int wave = tid >> 6, lane = tid & 63;
    int ln = lane & 15, quad = lane >> 4;
    int row = tid >> 2, kseg = (tid & 3) * 16;
    f32x4 acc[4] = {};
    bf16x8 pa0, pa1, pw0, pw1, pz0, pz1;
    float4 pf0, pf1, pf2, pf3;
    bf16x8 pc0[SPLIT], pc1[SPLIT];
    float pwt[SPLIT];
    auto prefetch = [&](int k0) {
        if constexpr (COMB) {
            int rowg = bm + row;
            int head = (k0 + kseg) >> 5;
            #pragma unroll
            for (int zz = 0; zz < SPLIT; zz++) {
                pwt[zz] = lsum[((size_t)zz*NH + head)*NN + rowg];
                const __bf16* p = &A[((size_t)zz*NN + rowg)*C + k0 + kseg];
                pc0[zz] = *(const bf16x8*)p;
                pc1[zz] = *(const bf16x8*)(p + 8);
            }
        } else {
            const __bf16* ap = &A[(size_t)(bm+row)*K + k0 + kseg];
            pa0 = *(const bf16x8*)ap;
            pa1 = *(const bf16x8*)(ap + 8);
            if constexpr (BN == 1) {
                const __bf16* p = &A2b[(size_t)(bm+row)*K + k0 + kseg];
                pz0 = *(const bf16x8*)p;
                pz1 = *(const bf16x8*)(p + 8);
            } else if (A2f) {
                const float* p = &A2f[(size_t)(bm+row)*K + k0 + kseg];
                pf0 = *(const float4*)p;
                pf1 = *(const float4*)(p+4);
                pf2 = *(const float4*)(p+8);
                pf3 = *(const float4*)(p+12);
            }
        }
        const __bf16* wp = &W[(size_t)(bn+row)*K + k0 + kseg];
        pw0 = *(const bf16x8*)wp;
        pw1 = *(const bf16x8*)(wp + 8);
    };
    prefetch(0);
    for (int k0 = 0; k0 < K; k0 += 64) {
        {   // transform prefetched regs and commit to LDS
            bf16x8 a0, a1;
            if constexpr (COMB) {
                float tot = 0.f;
                #pragma unroll
                for (int zz = 0; zz < SPLIT; zz++) tot += pwt[zz];
                float inv = 1.0f / tot;
                float v[16] = {};
                #pragma unroll
                for (int zz = 0; zz < SPLIT; zz++) {
                    #pragma unroll
                    for (int j = 0; j < 8; j++) {
                        v[j]   += pwt[zz]*(float)pc0[zz][j];
                        v[8+j] += pwt[zz]*(float)pc1[zz][j];
                    }
                }
                #pragma unroll
                for (int j = 0; j < 8; j++) {
                    a0[j] = (__bf16)(v[j]*inv);
                    a1[j] = (__bf16)(v[8+j]*inv);
                }
            } else {
                a0 = pa0;
                a1 = pa1;
                if constexpr (AAF) {
                    float asc[16], ash[16];
                    #pragma unroll
                    for (int i = 0; i < 4; i++) {
                        *(float4*)&asc[i*4] = *(const float4*)&acoefs[k0 + kseg + i*4];
                        *(float4*)&ash[i*4] = *(const float4*)&acoefs[C + k0 + kseg + i*4];
                    }
                    #pragma unroll
                    for (int j = 0; j < 8; j++) {
                        a0[j] = (__bf16)((float)a0[j]*asc[j] + ash[j]);
                        a1[j] = (__bf16)((float)a1[j]*asc[8+j] + ash[8+j]);
                    }
                }
                if constexpr (BN == 1) {
                    float sc1[16], sh1[16], sc2[16], sh2[16];
                    #pragma unroll
                    for (int i = 0; i < 4; i++) {
                        *(float4*)&sc1[i*4] = *(const float4*)&coefs[k0 + kseg + i*4];
                        *(float4*)&sh1[i*4] = *(const float4*)&coefs[C + k0 + kseg + i*4];
                        *(float4*)&sc2[i*4] = *(const float4*)&coefs[2*C + k0 + kseg + i*4];
                        *(float4*)&sh2[i*4] = *(const float4*)&coefs[3*C + k0 + kseg + i*4];
                    }
                    #pragma unroll
                    for (int j = 0; j < 8; j++) {
                        a0[j] = (__bf16)((float)a0[j]*sc1[j] + sh1[j]
                                       + (float)pz0[j]*sc2[j] + sh2[j]);
                        a1[j] = (__bf16)((float)a1[j]*sc1[8+j] + sh1[8+j]
                                       + (float)pz1[j]*sc2[8+j] + sh2[8+j]);
                    }
                } else if (A2f) {
                    a0[0]=(__bf16)((float)a0[0]+pf0.x); a0[1]=(__bf16)((float)a0[1]+pf0.y);
                    a0[2]=(__bf16)((float)a0[2]+pf0.z); a0[3]=(__bf16)((float)a0[3]+pf0.w);
                    a0[4]=(__bf16)((float)a0[4]+pf1.x); a0[5]=(__bf16)((float)a0[5]+pf1.y);
                    a0[6]=(__bf16)((float)a0[6]+pf1.z); a0[7]=(__bf16)((float)a0[7]+pf1.w);
                    a1[0]=(__bf16)((float)a1[0]+pf2.x); a1[1]=(__bf16)((float)a1[1]+pf2.y);
                    a1[2]=(__bf16)((float)a1[2]+pf2.z); a1[3]=(__bf16)((float)a1[3]+pf2.w);
                    a1[4]=(__bf16)((float)a1[4]+pf3.x); a1[5]=(__bf16)((float)a1[5]+pf3.y);
                    a1[6]=(__bf16)((float)a1[6]+pf3.z); a1[7]=(__bf16)((float)a1[7]+pf3.w);
                }
            }
            *(bf16x8*)&As[row*GS + kseg]     = a0;
            *(bf16x8*)&As[row*GS + kseg + 8] = a1;
            *(bf16x8*)&Ws[row*GS + kseg]     = pw0;
            *(bf16x8*)&Ws[row*GS + kseg + 8] = pw1;
        }
        __syncthreads();
        if (k0 + 64 < K) prefetch(k0 + 64);   // VMEM issues overlap MFMA below
        #pragma unroll
        for (int kt2 = 0; kt2 < 2; kt2++) {
            bf16x8 bfr = *(const bf16x8*)&Ws[(wave*16+ln)*GS + kt2*32 + quad*8];
            #pragma unroll
            for (int i = 0; i < 4; i++) {
                bf16x8 afr = *(const bf16x8*)&As[(i*16+ln)*GS + kt2*32 + quad*8];
                acc[i] = __builtin_amdgcn_mfma_f32_16x16x32_bf16(afr, bfr, acc[i], 0, 0, 0);
            }
        }
        __syncthreads();                      // LDS reads done before next write
    }
    int col = bn + wave*16 + ln;
    if constexpr (QKV) {
        float bsv = col < 256 ? b0[col] : (col < 512 ? b1[col-256] : b2[col-512]);
        if (col < 256) {
            #pragma unroll
            for (int i = 0; i < 4; i++)
                #pragma unroll
                for (int rr = 0; rr < 4; rr++)
                    out[(size_t)(bm + i*16 + quad*4 + rr)*C + col] =
                        (__bf16)((acc[i][rr] + bsv) * (float)QSCALE);
        } else if (col < 512) {
            int hd = (col-256) >> 5, dh = (col-256) & 31;
            #pragma unroll
            for (int i = 0; i < 4; i++)
                #pragma unroll
                for (int rr = 0; rr < 4; rr++)
                    ktp[((size_t)hd*NN + bm + i*16 + quad*4 + rr)*DH + dh] =
                        (__bf16)(acc[i][rr] + bsv);
        } else {
            int vrow = col - 512;
            #pragma unroll
            for (int i = 0; i < 4; i++) {
                bf16x4v pk = {(__bf16)(acc[i][0]+bsv), (__bf16)(acc[i][1]+bsv),
                              (__bf16)(acc[i][2]+bsv), (__bf16)(acc[i][3]+bsv)};
                *(bf16x4v*)&vt[(size_t)vrow*NN + bm + i*16 + quad*4] = pk;
            }
        }
        return;
    }
    float bsv = b0[col];
    float sc1 = 0.f, sh1 = 0.f, sc2 = 0.f, sh2 = 0.f;
    if constexpr (BN == 2) {
        float m1 = st1[col]*(1.f/NN);
        sc1 = rsqrtf(st1[C+col]*(1.f/NN) - m1*m1 + EPS) * g1[col];
        sh1 = bb1[col] - m1*sc1;
        float m2 = st2[col]*(1.f/NN);
        sc2 = rsqrtf(st2[C+col]*(1.f/NN) - m2*m2 + EPS) * g2[col];
        sh2 = bb2[col] - m2*sc2;
    }
    float r1sc = 1.f, r1sh = 0.f;
    if (rst3) {   // residual add1 is raw zbuf3 -> apply prev-layer bn3 per col
        float m3 = rst3[col]*(1.f/NN);
        r1sc = rsqrtf(rst3[C+col]*(1.f/NN) - m3*m3 + EPS) * rg3[col];
        r1sh = rb3[col] - m3*r1sc;
    }
    float ssum = 0.f, ssq = 0.f;
    #pragma unroll
    for (int i = 0; i < 4; i++) {
        #pragma unroll
        for (int rr = 0; rr < 4; rr++) {
            int rw = bm + i*16 + quad*4 + rr;
            float vv = acc[i][rr] + bsv;
            if (relu) vv = fmaxf(vv, 0.f);
            size_t idx = (size_t)rw*Nout + col;
            if constexpr (BN == 2) {
                vv += (float)add1[idx]*sc1 + sh1 + (float)add2[idx]*sc2 + sh2;
            } else {
                if (add1) {
                    float t1v = (float)add1[idx];
                    vv += rst3 ? (t1v*r1sc + r1sh) : t1v;
                }
                if (add2) vv += (float)add2[idx];
            }
            out[idx] = (__bf16)vv;
            ssum += vv; ssq += vv*vv;
        }
    }
    if (stats) {
        ssum += __shfl_xor(ssum, 16); ssum += __shfl_xor(ssum, 32);
        ssq  += __shfl_xor(ssq, 16);  ssq  += __shfl_xor(ssq, 32);
        if (quad == 0) {
            atomicAdd(&stats[col], ssum);
            atomicAdd(&stats[Nout + col], ssq);
        }
    }
}

// ---------------- attention body: 256-q tiles, SPLIT=4 (R25 config) ----------------
__device__ __forceinline__ void attn_body(int t, const __bf16* __restrict__ qbuf,
        const __bf16* __restrict__ kt, const __bf16* __restrict__ vt,
        __bf16* __restrict__ opart, float* __restrict__ lsum, __bf16* lds) {
    int head = t & 7, qi = (t >> 3) & 15, z = t >> 7;
    int qb = qi * QB;
    int hb = head * DH;
    int tid = threadIdx.x;
    int wave = tid >> 6, lane = tid & 63;
    int ln = lane & 15, quad = lane >> 4;
    __bf16* Kb0 = lds;                    // [128][36] = 4608 elems each
    __bf16* Kb1 = lds + 4608;
    __bf16* Vb0 = lds + 9216;             // [32][VS] = 4352 elems each
    __bf16* Vb1 = lds + 9216 + 32*VS;

    bf16x8 qf[4];
    #pragma unroll
    for (int g = 0; g < 4; g++)
        qf[g] = *(const bf16x8*)&qbuf[(size_t)(qb + wave*64 + g*16 + ln)*C + hb + quad*8];

    f32x4 ot[4][2] = {};
    f32x4 la[4] = {};
    const bf16x4s ones = {(short)0x3F80, (short)0x3F80, (short)0x3F80, (short)0x3F80};
    const f32x4 zz = {0.f,0.f,0.f,0.f};

    int srow = tid >> 1, sseg = (tid & 1) * 16;   // K staging: 2 threads/row (64B rows)
    int vd = tid >> 3, vseg = (tid & 7) * 16;     // V staging: 8 threads/dim-row
    int kt0 = z * KT8;
    const __bf16* kbase = &kt[(size_t)head*NN*DH];
    {   // prologue: stage tile (rotated start decorrelates VMEM bursts)
        int i0 = qi & (KT8-1);
        const __bf16* kp = &kbase[(size_t)((kt0+i0)*128 + srow)*DH + sseg];
        *(bf16x8*)&Kb0[srow*36 + sseg]     = *(const bf16x8*)kp;
        *(bf16x8*)&Kb0[srow*36 + sseg + 8] = *(const bf16x8*)(kp + 8);
        const __bf16* vp = &vt[(size_t)(hb + vd)*NN + (kt0+i0)*128 + vseg];
        *(bf16x8*)&Vb0[vd*VS + vseg]     = *(const bf16x8*)vp;
        *(bf16x8*)&Vb0[vd*VS + vseg + 8] = *(const bf16x8*)(vp + 8);
    }
    for (int ii = 0; ii < KT8; ii++) {
        int inext = (ii + 1 + qi) & (KT8-1);
        __bf16* Kc = (ii & 1) ? Kb1 : Kb0;
        __bf16* Kn = (ii & 1) ? Kb0 : Kb1;
        __bf16* Vc = (ii & 1) ? Vb1 : Vb0;
        __bf16* Vn = (ii & 1) ? Vb0 : Vb1;
        __syncthreads();                       // Kc/Vc writes visible
        bf16x8 nk0, nk1, nv0, nv1;
        bool hasNext = (ii + 1 < KT8);
        if (hasNext) {                          // next-tile loads overlap compute
            const __bf16* kp = &kbase[(size_t)((kt0+inext)*128 + srow)*DH + sseg];
            nk0 = *(const bf16x8*)kp;
            nk1 = *(const bf16x8*)(kp + 8);
            const __bf16* vp = &vt[(size_t)(hb + vd)*NN + (kt0+inext)*128 + vseg];
            nv0 = *(const bf16x8*)vp;
            nv1 = *(const bf16x8*)(vp + 8);
        }
        #pragma unroll
        for (int pr = 0; pr < 4; pr++) {
            #pragma unroll
            for (int s = 0; s < 2; s++) {
                int ks = pr*2 + s;
                bf16x8 kf = *(const bf16x8*)&Kc[(ks*16+ln)*36 + quad*8];
                bf16x4s vf0 = *(const bf16x4s*)&Vc[(0*16+ln)*VS + ks*16 + quad*4];
                bf16x4s vf1 = *(const bf16x4s*)&Vc[(1*16+ln)*VS + ks*16 + quad*4];
                f32x4 st0 = __builtin_amdgcn_mfma_f32_16x16x32_bf16(kf, qf[0], zz, 0, 0, 0);
                f32x4 st1 = __builtin_amdgcn_mfma_f32_16x16x32_bf16(kf, qf[1], zz, 0, 0, 0);
                f32x4 st2 = __builtin_amdgcn_mfma_f32_16x16x32_bf16(kf, qf[2], zz, 0, 0, 0);
                f32x4 st3 = __builtin_amdgcn_mfma_f32_16x16x32_bf16(kf, qf[3], zz, 0, 0, 0);
                union { __bf16 b[4]; bf16x4s s; } pf0, pf1, pf2, pf3;
                #pragma unroll
                for (int rr = 0; rr < 4; rr++) {
                    pf0.b[rr] = (__bf16)__builtin_amdgcn_exp2f(st0[rr]);
                    pf1.b[rr] = (__bf16)__builtin_amdgcn_exp2f(st1[rr]);
                    pf2.b[rr] = (__bf16)__builtin_amdgcn_exp2f(st2[rr]);
                    pf3.b[rr] = (__bf16)__builtin_amdgcn_exp2f(st3[rr]);
                }
                ot[0][0] = __builtin_amdgcn_mfma_f32_16x16x16bf16_1k(vf0, pf0.s, ot[0][0], 0, 0, 0);
                ot[0][1] = __builtin_amdgcn_mfma_f32_16x16x16bf16_1k(vf1, pf0.s, ot[0][1], 0, 0, 0);
                ot[1][0] = __builtin_amdgcn_mfma_f32_16x16x16bf16_1k(vf0, pf1.s, ot[1][0], 0, 0, 0);
                ot[1][1] = __builtin_amdgcn_mfma_f32_16x16x16bf16_1k(vf1, pf1.s, ot[1][1], 0, 0, 0);
                ot[2][0] = __builtin_amdgcn_mfma_f32_16x16x16bf16_1k(vf0, pf2.s, ot[2][0], 0, 0, 0);
                ot[2][1] = __builtin_amdgcn_mfma_f32_16x16x16bf16_1k(vf1, pf2.s, ot[2][1], 0, 0, 0);
                ot[3][0] = __builtin_amdgcn_mfma_f32_16x16x16bf16_1k(vf0, pf3.s, ot[3][0], 0, 0, 0);
                ot[3][1] = __builtin_amdgcn_mfma_f32_16x16x16bf16_1k(vf1, pf3.s, ot[3][1], 0, 0, 0);
                la[0]    = __builtin_amdgcn_mfma_f32_16x16x16bf16_1k(ones, pf0.s, la[0], 0, 0, 0);
                la[1]    = __builtin_amdgcn_mfma_f32_16x16x16bf16_1k(ones, pf1.s, la[1], 0, 0, 0);
                la[2]    = __builtin_amdgcn_mfma_f32_16x16x16bf16_1k(ones, pf2.s, la[2], 0, 0, 0);
                la[3]    = __builtin_amdgcn_mfma_f32_16x16x16bf16_1k(ones, pf3.s, la[3], 0, 0, 0);
            }
        }
        if (hasNext) {
            *(bf16x8*)&Kn[srow*36 + sseg]     = nk0;
            *(bf16x8*)&Kn[srow*36 + sseg + 8] = nk1;
            *(bf16x8*)&Vn[vd*VS + vseg]     = nv0;
            *(bf16x8*)&Vn[vd*VS + vseg + 8] = nv1;
        }
    }
    #pragma unroll
    for (int g = 0; g < 4; g++) {
        float l_ = la[g][0];
        float inv = 1.0f / l_;
        int qrow = qb + wave*64 + g*16 + ln;
        #pragma unroll
        for (int h = 0; h < 2; h++) {
            bf16x4v pk = {(__bf16)(ot[g][h][0]*inv), (__bf16)(ot[g][h][1]*inv),
                          (__bf16)(ot[g][h][2]*inv), (__bf16)(ot[g][h][3]*inv)};
            *(bf16x4v*)&opart[((size_t)z*NN + qrow)*C + hb + h*16 + quad*4] = pk;
        }
        if (quad == 0)
            lsum[((size_t)z*NH + head)*NN + qrow] = l_;
    }
}

// ---------------- kernel 1: QKV gemm + CSR gather agg (bn3 fold on srcH) ----------
__global__ __launch_bounds__(256) void qkv_agg_kernel(const __bf16* __restrict__ srcH,
        const __bf16* __restrict__ Wqkv, const float* __restrict__ bq,
        const float* __restrict__ bk, const float* __restrict__ bv,
        __bf16* __restrict__ qout, __bf16* __restrict__ ktout,
        __bf16* __restrict__ vtout,
        const int* __restrict__ rowptr, const int* __restrict__ eidsrc,
        float* __restrict__ agg,
        const float* __restrict__ st3p, const float* __restrict__ g3p,
        const float* __restrict__ b3p) {
    __shared__ __bf16 lds[9216];
    __shared__ float coefs[2*C];
    int tid = threadIdx.x;
    if (st3p) {
        float m = st3p[tid]*(1.f/NN);
        float sc = rsqrtf(st3p[C+tid]*(1.f/NN) - m*m + EPS) * g3p[tid];
        coefs[tid] = sc; coefs[C+tid] = b3p[tid] - m*sc;
    } else { coefs[tid] = 1.f; coefs[C+tid] = 0.f; }
    __syncthreads();
    int bx = blockIdx.x;
    if (bx < 768) {
        gemm_core<1,0,0,1>((bx & 63)*64, (bx >> 6)*64, srcH, nullptr, nullptr, Wqkv,
                bq, bk, bv, nullptr, nullptr, qout, vtout, ktout, nullptr,
                nullptr, nullptr, nullptr, nullptr, nullptr, nullptr, nullptr,
                nullptr, coefs, nullptr, nullptr, nullptr,
                C, 768, 0, lds, lds + 4608);
        return;
    }
    int wave = tid >> 6, lane = tid & 63;
    float4 sc4 = *(const float4*)&coefs[lane*4];
    float4 sh4 = *(const float4*)&coefs[C + lane*4];
    int node = (bx - 768)*4 + wave;
    int beg = rowptr[node], end = rowptr[node+1];
    float s0 = 0.f, s1 = 0.f, s2 = 0.f, s3 = 0.f;
    for (int e = beg; e < end; e++) {
        int src = eidsrc[e];
        bf16x4v hv = *(const bf16x4v*)&srcH[(size_t)src*C + lane*4];
        s0 += sc4.x*(float)hv[0] + sh4.x;
        s1 += sc4.y*(float)hv[1] + sh4.y;
        s2 += sc4.z*(float)hv[2] + sh4.z;
        s3 += sc4.w*(float)hv[3] + sh4.w;
    }
    float4 o = {s0, s1, s2, s3};
    *(float4*)&agg[(size_t)node*C + lane*4] = o;
}

// ---------------- kernel 2: GIN gemm1 (first, drains early) + attention ----------------
__global__ __launch_bounds__(256, 2) void gin1_attn_kernel(const __bf16* __restrict__ srcH,
        const float* __restrict__ agg, const __bf16* __restrict__ gw1,
        const float* __restrict__ gb1, __bf16* __restrict__ t1,
        const __bf16* __restrict__ qbuf, const __bf16* __restrict__ kt,
        const __bf16* __restrict__ vt,
        __bf16* __restrict__ opart, float* __restrict__ lsum,
        const float* __restrict__ st3p, const float* __restrict__ g3p,
        const float* __restrict__ b3p) {
    __shared__ __bf16 lds[17920];     // attn 17920; gemm uses first 9216
    __shared__ float coefs[2*C];
    int tid = threadIdx.x;
    if (st3p) {
        float m = st3p[tid]*(1.f/NN);
        float sc = rsqrtf(st3p[C+tid]*(1.f/NN) - m*m + EPS) * g3p[tid];
        coefs[tid] = sc; coefs[C+tid] = b3p[tid] - m*sc;
    } else { coefs[tid] = 1.f; coefs[C+tid] = 0.f; }
    __syncthreads();
    int bx = blockIdx.x;
    if (bx < 256) {
        gemm_core<0,0,0,1>((bx >> 2)*64, (bx & 3)*64, srcH, agg, nullptr, gw1,
                gb1, nullptr, nullptr, nullptr, nullptr, t1, nullptr, nullptr,
                nullptr, nullptr, nullptr, nullptr, nullptr, nullptr, nullptr,
                nullptr, nullptr, coefs, nullptr, nullptr, nullptr,
                C, C, 1, lds, lds + 4608);
        return;
    }
    attn_body(bx - 256, qbuf, kt, vt, opart, lsum, lds);
}

// ---------------- kernel 3: GIN gemm2 + proj-with-combine (bn3 fold on residual) ------
__global__ __launch_bounds__(256) void gin2_proj_kernel(const __bf16* __restrict__ t1,
        const __bf16* __restrict__ gw2, const float* __restrict__ gb2,
        const __bf16* __restrict__ srcH, __bf16* __restrict__ z1, float* __restrict__ st1,
        const __bf16* __restrict__ opart, const float* __restrict__ lsum,
        const __bf16* __restrict__ wop, const float* __restrict__ lbo,
        __bf16* __restrict__ z2, float* __restrict__ st2,
        const float* __restrict__ st3p, const float* __restrict__ g3p,
        const float* __restrict__ b3p) {
    __shared__ __bf16 lds[9216];
    int bx = blockIdx.x;
    if (bx < 256) {
        gemm_core<0,0,0,0>((bx >> 2)*64, (bx & 3)*64, t1, nullptr, nullptr, gw2,
                gb2, nullptr, nullptr, srcH, nullptr, z1, nullptr, nullptr, st1,
                nullptr, nullptr, nullptr, nullptr, nullptr, nullptr, nullptr,
                nullptr, nullptr, st3p, g3p, b3p,
                C, C, 0, lds, lds + 4608);
        return;
    }
    int t = bx - 256;
    gemm_core<0,0,1,0>((t >> 2)*64, (t & 3)*64, opart, nullptr, nullptr, wop,
            lbo, nullptr, nullptr, srcH, nullptr, z2, nullptr, nullptr, st2,
            nullptr, nullptr, nullptr, nullptr, nullptr, nullptr, nullptr,
            lsum, nullptr, st3p, g3p, b3p,
            C, C, 0, lds, lds + 4608);
}

// ---------------- kernel 4: ff1 with inline bn1/bn2 on staging ----------------
__global__ __launch_bounds__(256) void ff1_kernel(const __bf16* __restrict__ z1,
        const __bf16* __restrict__ z2, const __bf16* __restrict__ mw1,
        const float* __restrict__ lmb1, __bf16* __restrict__ hidden,
        const float* __restrict__ st1, const float* __restrict__ g1,
        const float* __restrict__ bb1, const float* __restrict__ st2,
        const float* __restrict__ g2, const float* __restrict__ bb2) {
    __shared__ __bf16 lds[9216];
    __shared__ float coefs[4*C];
    int tid = threadIdx.x;
    {   // fold BN stats -> (scale, shift) per channel, in LDS
        float m = st1[tid]*(1.f/NN);
        float var = st1[C+tid]*(1.f/NN) - m*m;
        float s = rsqrtf(var + EPS) * g1[tid];
        coefs[tid] = s; coefs[C+tid] = bb1[tid] - m*s;
        m = st2[tid]*(1.f/NN);
        var = st2[C+tid]*(1.f/NN) - m*m;
        s = rsqrtf(var + EPS) * g2[tid];
        coefs[2*C+tid] = s; coefs[3*C+tid] = bb2[tid] - m*s;
    }
    __syncthreads();   // staging reads coefs before gemm_core's first barrier
    int bx = blockIdx.x;
    gemm_core<0,1,0,0>((bx >> 3)*64, (bx & 7)*64, z1, nullptr, z2, mw1,
            lmb1, nullptr, nullptr, nullptr, nullptr, hidden, nullptr, nullptr,
            nullptr, coefs, nullptr, nullptr, nullptr, nullptr, nullptr, nullptr,
            nullptr, nullptr, nullptr, nullptr, nullptr,
            C, 2*C, 1, lds, lds + 4608);
}

// ---------------- kernel 5: ff2 with inline bn residuals in epilogue ----------------
__global__ __launch_bounds__(256) void ff2_kernel(const __bf16* __restrict__ hidden,
        const __bf16* __restrict__ mw2, const float* __restrict__ lmb2,
        const __bf16* __restrict__ z1, const __bf16* __restrict__ z2,
        __bf16* __restrict__ zbuf3, float* __restrict__ st3,
        const float* __restrict__ st1, const float* __restrict__ g1,
        const float* __restrict__ bb1, const float* __restrict__ st2,
        const float* __restrict__ g2, const float* __restrict__ bb2) {
    __shared__ __bf16 lds[9216];
    int bx = blockIdx.x;
    gemm_core<0,2,0,0>((bx >> 2)*64, (bx & 3)*64, hidden, nullptr, nullptr, mw2,
            lmb2, nullptr, nullptr, z1, z2, zbuf3, nullptr, nullptr, st3,
            nullptr, st1, g1, bb1, st2, g2, bb2,
            nullptr, nullptr, nullptr, nullptr, nullptr,
            2*C, C, 0, lds, lds + 4608);
}

// ---------------- BatchNorm apply (final layer only) ----------------
__global__ __launch_bounds__(256) void bn_apply_kernel(const __bf16* __restrict__ z,
        const float* __restrict__ stats, const float* __restrict__ g,
        const float* __restrict__ b, float* __restrict__ outf) {
    int idx4 = (blockIdx.x*256 + threadIdx.x) * 4;
    int c = idx4 & (C-1);
    bf16x4v zv = *(const bf16x4v*)&z[idx4];
    float4 st = *(const float4*)&stats[c];
    float4 sq = *(const float4*)&stats[C + c];
    float4 gv = *(const float4*)&g[c];
    float4 bv = *(const float4*)&b[c];
    float o[4];
    float m0 = st.x*(1.f/NN), m1 = st.y*(1.f/NN), m2 = st.z*(1.f/NN), m3 = st.w*(1.f/NN);
    o[0] = ((float)zv[0] - m0) * rsqrtf(sq.x*(1.f/NN) - m0*m0 + EPS) * gv.x + bv.x;
    o[1] = ((float)zv[1] - m1) * rsqrtf(sq.y*(1.f/NN) - m1*m1 + EPS) * gv.y + bv.y;
    o[2] = ((float)zv[2] - m2) * rsqrtf(sq.z*(1.f/NN) - m2*m2 + EPS) * gv.z + bv.z;
    o[3] = ((float)zv[3] - m3) * rsqrtf(sq.w*(1.f/NN) - m3*m3 + EPS) * gv.w + bv.w;
    float4 ov = {o[0], o[1], o[2], o[3]};
    *(float4*)&outf[idx4] = ov;
}

extern "C" void kernel_launch(void* const* d_in, const int* in_sizes, int n_in,
                              void* d_out, int out_size, void* d_ws, size_t ws_size,
                              hipStream_t stream) {
    const float* x      = (const float*)d_in[0];
    const int*   ei     = (const int*)d_in[1];
    const float* lin1_w = (const float*)d_in[2];
    const float* lin1_b = (const float*)d_in[3];
    const float* gin_w1 = (const float*)d_in[4];
    const float* gin_b1 = (const float*)d_in[5];
    const float* gin_w2 = (const float*)d_in[6];
    const float* gin_b2 = (const float*)d_in[7];
    const float* wq = (const float*)d_in[8];
    const float* wk = (const float*)d_in[9];
    const float* wv = (const float*)d_in[10];
    const float* wo = (const float*)d_in[11];
    const float* bq = (const float*)d_in[12];
    const float* bk = (const float*)d_in[13];
    const float* bv = (const float*)d_in[14];
    const float* bo = (const float*)d_in[15];
    const float* bn1_g = (const float*)d_in[16];
    const float* bn1_b = (const float*)d_in[17];
    const float* bn2_g = (const float*)d_in[18];
    const float* bn2_b = (const float*)d_in[19];
    const float* bn3_g = (const float*)d_in[20];
    const float* bn3_b = (const float*)d_in[21];
    const float* mw1 = (const float*)d_in[22];
    const float* mb1 = (const float*)d_in[23];
    const float* mw2 = (const float*)d_in[24];
    const float* mb2 = (const float*)d_in[25];

    const size_t MB = 1u << 20;
    char* ws = (char*)d_ws;
    __bf16* Hb      = (__bf16*)(ws);            // 2 MB  layer-0 input (lin1 output)
    __bf16* z1      = (__bf16*)(ws + 2*MB);     // 2 MB  GIN pre-bn1
    __bf16* zbuf3   = (__bf16*)(ws + 4*MB);     // 2 MB  raw pre-bn3 (consumed with fold)
    __bf16* z2      = (__bf16*)(ws + 6*MB);     // 2 MB  attn pre-bn2
    __bf16* t1      = (__bf16*)(ws + 8*MB);     // 2 MB  GIN hidden
    __bf16* Qbuf    = (__bf16*)(ws + 10*MB);    // 2 MB  [N][C] (QSCALE folded)
    __bf16* Ktb     = (__bf16*)(ws + 12*MB);    // 2 MB  [NH][NN][DH] head-major K
    __bf16* Vt      = (__bf16*)(ws + 14*MB);    // 2 MB  [C][N]
    float*  agg     = (float*)(ws + 16*MB);     // 4 MB  (dead after gin1)
    __bf16* hiddenb = (__bf16*)(ws + 16*MB);    // 4 MB  shares agg region (agg dead
                                                //       after gin1; hidden lives k4->k5)
    __bf16* Opart   = (__bf16*)(ws + 20*MB);    // 8 MB  (SPLIT=4)
    __bf16* Wb      = (__bf16*)(ws + 28*MB);    // 3.93 MB
    float*  stats   = (float*)(ws + 32*MB);     // 9 x 2C
    int*    cursor  = (int*)(ws + 32*MB + 64*1024);
    int*    rowptr  = (int*)(ws + 32*MB + 96*1024);
    int*    eidsrc  = (int*)(ws + 32*MB + 128*1024);
    float*  lsum    = (float*)(ws + 33*MB);     // 0.5 MB (SPLIT=4), dedicated

    dim3 blk(256);

    prep_w<<<dim3(384, 8), blk, 0, stream>>>(gin_w1, gin_w2, wq, wk, wv, wo, mw1, mw2, Wb);
    hipMemsetAsync(stats, 0, 9 * 2 * C * sizeof(float), stream);
    lin1_kernel<<<NN, blk, 0, stream>>>(x, lin1_w, lin1_b, Hb);
    hipMemsetAsync(cursor, 0, NN * sizeof(int), stream);
    hist_kernel<<<NE/256, blk, 0, stream>>>(ei, cursor);
    scan_kernel<<<1, blk, 0, stream>>>(cursor, rowptr, cursor);
    fill_kernel<<<NE/256, blk, 0, stream>>>(ei, cursor, eidsrc);

    for (int l = 0; l < NL; l++) {
        const __bf16* gw1b = Wb + (size_t)l*CC1;
        const __bf16* gw2b = Wb + (size_t)(3+l)*CC1;
        const __bf16* wqkv = Wb + (size_t)(6+3*l)*CC1;
        const __bf16* wop  = Wb + (size_t)(15+l)*CC1;
        const __bf16* mw1p = Wb + (size_t)(18+2*l)*CC1;
        const __bf16* mw2p = Wb + (size_t)(24+2*l)*CC1;
        const float* gb1 = gin_b1 + (size_t)l*C;
        const float* gb2 = gin_b2 + (size_t)l*C;
        const float* lbq = bq + (size_t)l*C;
        const float* lbk = bk + (size_t)l*C;
        const float* lbv = bv + (size_t)l*C;
        const float* lbo = bo + (size_t)l*C;
        const float* lmb1 = mb1 + (size_t)l*2*C;
        const float* lmb2 = mb2 + (size_t)l*C;
        float* st1 = stats + (size_t)l*3*2*C;
        float* st2 = st1 + 2*C;
        float* st3 = st2 + 2*C;
        const float* g1v = bn1_g + (size_t)l*C; const float* b1v = bn1_b + (size_t)l*C;
        const float* g2v = bn2_g + (size_t)l*C; const float* b2v = bn2_b + (size_t)l*C;

        // bn3 fold: layer l>=1 consumes raw zbuf3 + prev layer's bn3 affine
        const __bf16* srcH = (l == 0) ? Hb : zbuf3;
        const float* st3p = (l == 0) ? nullptr : stats + (size_t)(l-1)*3*2*C + 4*C;
        const float* g3p  = (l == 0) ? nullptr : bn3_g + (size_t)(l-1)*C;
        const float* b3p  = (l == 0) ? nullptr : bn3_b + (size_t)(l-1)*C;

        // 1. stacked-QKV projection (Q / head-major K / V^T) + gather aggregation
        qkv_agg_kernel<<<768 + NN/4, blk, 0, stream>>>(srcH, wqkv, lbq, lbk, lbv,
                Qbuf, Ktb, Vt, rowptr, eidsrc, agg, st3p, g3p, b3p);
        // 2. GIN gemm1 (first, drains early) + flash attention (256-q, SPLIT=4)
        gin1_attn_kernel<<<256 + ATTN_BLKS, blk, 0, stream>>>(srcH, agg,
                gw1b, gb1, t1, Qbuf, Ktb, Vt, Opart, lsum, st3p, g3p, b3p);
        // 3. GIN gemm2 + proj-with-inline-combine (residual = bn3(zbuf3))
        gin2_proj_kernel<<<512, blk, 0, stream>>>(t1, gw2b, gb2, srcH, z1, st1,
                Opart, lsum, wop, lbo, z2, st2, st3p, g3p, b3p);
        // 4. ff1: bn1(z1)+bn2(z2) folded into staging
        ff1_kernel<<<512, blk, 0, stream>>>(z1, z2, mw1p, lmb1, hiddenb,
                st1, g1v, b1v, st2, g2v, b2v);
        // 5. ff2: bn residuals in epilogue, writes raw zbuf3
        ff2_kernel<<<256, blk, 0, stream>>>(hiddenb, mw2p, lmb2, z1, z2,
                zbuf3, st3, st1, g1v, b1v, st2, g2v, b2v);
        // 6. bn3 apply only for the final layer (f32 output)
        if (l == NL-1)
            bn_apply_kernel<<<NN/4, blk, 0, stream>>>(zbuf3, st3,
                    bn3_g + (size_t)l*C, bn3_b + (size_t)l*C, (float*)d_out);
    }
}

// Round 13
// 389.578 us; speedup vs baseline: 7.1980x; 1.0114x over previous
//
#include <hip/hip_runtime.h>

#define NN 4096
#define NE 65536
#define C 256
#define NL 3
#define NH 8
#define DH 32
#define EPS 1e-5f
#define SPLIT 4              // R25: 256-q tiles x SPLIT=4 -> 512 blocks (2/CU), KT8=8
#define KT8 (NN/128/SPLIT)   // 128-key tiles per split = 8
#define QB 256               // q rows per attn block
#define VS 136               // V LDS row stride in bf16
#define ATTN_BLKS ((NN/QB)*NH*SPLIT)   // 512

typedef __bf16 bf16x8 __attribute__((ext_vector_type(8)));
typedef __bf16 bf16x4v __attribute__((ext_vector_type(4)));
typedef float f32x4 __attribute__((ext_vector_type(4)));
typedef short bf16x4s __attribute__((ext_vector_type(4)));   // 4 bf16 as i16x4

// scale * log2(e), folded into Q at projection time so softmax uses exp2
#define QSCALE (0.17677669529663687f * 1.4426950408889634f)

#define CC1 (C*C)            // 65536
#define GS 72                // LDS row stride in bf16 (144 B: 2-way alias, free)

// ---------------- weight prep: fp32 -> bf16; qkv stacked per layer ----------------
// Wb layout (units of CC1): gw1 @0 (3), gw2 @3 (3), qkv @6 (9: layer l at 6+3l,
// order q,k,v), wo @15 (3), mw1 @18 (6), mw2 @24 (6). Total 30 CC1.
__global__ __launch_bounds__(256) void prep_w(const float* __restrict__ s0,
        const float* __restrict__ s1, const float* __restrict__ s2,
        const float* __restrict__ s3, const float* __restrict__ s4,
        const float* __restrict__ s5, const float* __restrict__ s6,
        const float* __restrict__ s7, __bf16* __restrict__ dst) {
    int g = blockIdx.y;
    int i = (blockIdx.x*256 + threadIdx.x)*4;
    const float* src; int n;
    switch (g) {
        case 0: src=s0; n=3*CC1; break;
        case 1: src=s1; n=3*CC1; break;
        case 2: src=s2; n=3*CC1; break;
        case 3: src=s3; n=3*CC1; break;
        case 4: src=s4; n=3*CC1; break;
        case 5: src=s5; n=3*CC1; break;
        case 6: src=s6; n=6*CC1; break;
        default: src=s7; n=6*CC1; break;
    }
    if (i >= n) return;
    size_t off;
    if (g >= 2 && g <= 4) {
        int l = i >> 16, rem = i & (CC1-1);
        off = (size_t)(6 + 3*l + (g-2))*CC1 + rem;
    } else {
        size_t base = (g==0) ? 0 : (g==1) ? 3*(size_t)CC1 : (g==5) ? 15*(size_t)CC1
                    : (g==6) ? 18*(size_t)CC1 : 24*(size_t)CC1;
        off = base + i;
    }
    float4 t = *(const float4*)(src + i);
    bf16x4v o = {(__bf16)t.x, (__bf16)t.y, (__bf16)t.z, (__bf16)t.w};
    *(bf16x4v*)(dst + off) = o;
}

// ---------------- lin1 ----------------
__global__ __launch_bounds__(256) void lin1_kernel(const float* __restrict__ x,
        const float* __restrict__ w, const float* __restrict__ b,
        __bf16* __restrict__ out) {
    int n = blockIdx.x, c = threadIdx.x;
    out[(size_t)n*C + c] = (__bf16)(x[n]*w[c] + b[c]);
}

// ---------------- CSR build ----------------
__global__ __launch_bounds__(256) void hist_kernel(const int* __restrict__ ei,
        int* __restrict__ cnt) {
    int e = blockIdx.x*256 + threadIdx.x;
    atomicAdd(&cnt[ei[NE + e]], 1);
}

__global__ __launch_bounds__(256) void scan_kernel(const int* __restrict__ cnt,
        int* __restrict__ rowptr, int* __restrict__ cursor) {
    __shared__ int tot[256];
    __shared__ int pre[257];
    int t = threadIdx.x;
    int base = t*16;
    int local[16];
    int s = 0;
    #pragma unroll
    for (int i = 0; i < 16; i++) { local[i] = s; s += cnt[base+i]; }
    tot[t] = s;
    __syncthreads();
    if (t == 0) {
        int acc = 0;
        for (int i = 0; i < 256; i++) { pre[i] = acc; acc += tot[i]; }
        pre[256] = acc;
    }
    __syncthreads();
    int off = pre[t];
    #pragma unroll
    for (int i = 0; i < 16; i++) {
        rowptr[base+i] = off + local[i];
        cursor[base+i] = off + local[i];
    }
    if (t == 0) rowptr[NN] = pre[256];
}

__global__ __launch_bounds__(256) void fill_kernel(const int* __restrict__ ei,
        int* __restrict__ cursor, int* __restrict__ eidsrc) {
    int e = blockIdx.x*256 + threadIdx.x;
    int dst = ei[NE + e], src = ei[e];
    int pos = atomicAdd(&cursor[dst], 1);
    eidsrc[pos] = src;
}

// ---------------- GEMM core, BK=64, R27: register-prefetch staging ----------------
// Register-prefetch pattern: loads for tile k+1 issue right after the barrier,
// overlap the MFMA of tile k, and their vmcnt wait lands in the NEXT
// iteration's transform (fully covered).
// QKV: Nout=768; col<256 -> Q*QSCALE; col<512 -> K head-major; else V^T
// BN==1: staging computes bn1(A)+bn2(A2b) via LDS coefs (caller must sync
//        after writing coefs -- staging reads them before first barrier!)
// BN==2: epilogue adds bn1(add1)+bn2(add2) from st/g/b per col
// COMB: A is Opart[z][NN][C]; staging does l-weighted split-K combine
template<int QKV, int BN, int COMB>
__device__ __forceinline__ void gemm_core(int bm, int bn,
        const __bf16* A, const float* A2f, const __bf16* A2b, const __bf16* W,
        const float* b0, const float* b1, const float* b2,
        const __bf16* add1, const __bf16* add2,
        __bf16* out, __bf16* vt, __bf16* ktp, float* stats,
        const float* coefs,    // LDS coef table (BN==1)
        const float* st1, const float* g1, const float* bb1,
        const float* st2, const float* g2, const float* bb2,   // BN==2
        const float* lsum,     // COMB
        int K, int Nout, int relu, __bf16* As, __bf16* Ws) {
    int tid = threadIdx.x;
    int wave = tid >> 6, lane = tid & 63;
    int ln = lane & 15, quad = lane >> 4;
    int row = tid >> 2, kseg = (tid & 3) * 16;
    f32x4 acc[4] = {};
    bf16x8 pa0, pa1, pw0, pw1, pz0, pz1;
    float4 pf0, pf1, pf2, pf3;
    bf16x8 pc0[SPLIT], pc1[SPLIT];
    float pwt[SPLIT];
    auto prefetch = [&](int k0) {
        if constexpr (COMB) {
            int rowg = bm + row;
            int head = (k0 + kseg) >> 5;
            #pragma unroll
            for (int zz = 0; zz < SPLIT; zz++) {
                pwt[zz] = lsum[((size_t)zz*NH + head)*NN + rowg];
                const __bf16* p = &A[((size_t)zz*NN + rowg)*C + k0 + kseg];
                pc0[zz] = *(const bf16x8*)p;
                pc1[zz] = *(const bf16x8*)(p + 8);
            }
        } else {
            const __bf16* ap = &A[(size_t)(bm+row)*K + k0 + kseg];
            pa0 = *(const bf16x8*)ap;
            pa1 = *(const bf16x8*)(ap + 8);
            if constexpr (BN == 1) {
                const __bf16* p = &A2b[(size_t)(bm+row)*K + k0 + kseg];
                pz0 = *(const bf16x8*)p;
                pz1 = *(const bf16x8*)(p + 8);
            } else if (A2f) {
                const float* p = &A2f[(size_t)(bm+row)*K + k0 + kseg];
                pf0 = *(const float4*)p;
                pf1 = *(const float4*)(p+4);
                pf2 = *(const float4*)(p+8);
                pf3 = *(const float4*)(p+12);
            }
        }
        const __bf16* wp = &W[(size_t)(bn+row)*K + k0 + kseg];
        pw0 = *(const bf16x8*)wp;
        pw1 = *(const bf16x8*)(wp + 8);
    };
    prefetch(0);
    for (int k0 = 0; k0 < K; k0 += 64) {
        {   // transform prefetched regs and commit to LDS
            bf16x8 a0, a1;
            if constexpr (COMB) {
                float tot = 0.f;
                #pragma unroll
                for (int zz = 0; zz < SPLIT; zz++) tot += pwt[zz];
                float inv = 1.0f / tot;
                float v[16] = {};
                #pragma unroll
                for (int zz = 0; zz < SPLIT; zz++) {
                    #pragma unroll
                    for (int j = 0; j < 8; j++) {
                        v[j]   += pwt[zz]*(float)pc0[zz][j];
                        v[8+j] += pwt[zz]*(float)pc1[zz][j];
                    }
                }
                #pragma unroll
                for (int j = 0; j < 8; j++) {
                    a0[j] = (__bf16)(v[j]*inv);
                    a1[j] = (__bf16)(v[8+j]*inv);
                }
            } else {
                a0 = pa0;
                a1 = pa1;
                if constexpr (BN == 1) {
                    float sc1[16], sh1[16], sc2[16], sh2[16];
                    #pragma unroll
                    for (int i = 0; i < 4; i++) {
                        *(float4*)&sc1[i*4] = *(const float4*)&coefs[k0 + kseg + i*4];
                        *(float4*)&sh1[i*4] = *(const float4*)&coefs[C + k0 + kseg + i*4];
                        *(float4*)&sc2[i*4] = *(const float4*)&coefs[2*C + k0 + kseg + i*4];
                        *(float4*)&sh2[i*4] = *(const float4*)&coefs[3*C + k0 + kseg + i*4];
                    }
                    #pragma unroll
                    for (int j = 0; j < 8; j++) {
                        a0[j] = (__bf16)((float)a0[j]*sc1[j] + sh1[j]
                                       + (float)pz0[j]*sc2[j] + sh2[j]);
                        a1[j] = (__bf16)((float)a1[j]*sc1[8+j] + sh1[8+j]
                                       + (float)pz1[j]*sc2[8+j] + sh2[8+j]);
                    }
                } else if (A2f) {
                    a0[0]=(__bf16)((float)a0[0]+pf0.x); a0[1]=(__bf16)((float)a0[1]+pf0.y);
                    a0[2]=(__bf16)((float)a0[2]+pf0.z); a0[3]=(__bf16)((float)a0[3]+pf0.w);
                    a0[4]=(__bf16)((float)a0[4]+pf1.x); a0[5]=(__bf16)((float)a0[5]+pf1.y);
                    a0[6]=(__bf16)((float)a0[6]+pf1.z); a0[7]=(__bf16)((float)a0[7]+pf1.w);
                    a1[0]=(__bf16)((float)a1[0]+pf2.x); a1[1]=(__bf16)((float)a1[1]+pf2.y);
                    a1[2]=(__bf16)((float)a1[2]+pf2.z); a1[3]=(__bf16)((float)a1[3]+pf2.w);
                    a1[4]=(__bf16)((float)a1[4]+pf3.x); a1[5]=(__bf16)((float)a1[5]+pf3.y);
                    a1[6]=(__bf16)((float)a1[6]+pf3.z); a1[7]=(__bf16)((float)a1[7]+pf3.w);
                }
            }
            *(bf16x8*)&As[row*GS + kseg]     = a0;
            *(bf16x8*)&As[row*GS + kseg + 8] = a1;
            *(bf16x8*)&Ws[row*GS + kseg]     = pw0;
            *(bf16x8*)&Ws[row*GS + kseg + 8] = pw1;
        }
        __syncthreads();
        if (k0 + 64 < K) prefetch(k0 + 64);   // VMEM issues overlap MFMA below
        #pragma unroll
        for (int kt2 = 0; kt2 < 2; kt2++) {
            bf16x8 bfr = *(const bf16x8*)&Ws[(wave*16+ln)*GS + kt2*32 + quad*8];
            #pragma unroll
            for (int i = 0; i < 4; i++) {
                bf16x8 afr = *(const bf16x8*)&As[(i*16+ln)*GS + kt2*32 + quad*8];
                acc[i] = __builtin_amdgcn_mfma_f32_16x16x32_bf16(afr, bfr, acc[i], 0, 0, 0);
            }
        }
        __syncthreads();                      // LDS reads done before next write
    }
    int col = bn + wave*16 + ln;
    if constexpr (QKV) {
        float bsv = col < 256 ? b0[col] : (col < 512 ? b1[col-256] : b2[col-512]);
        if (col < 256) {
            #pragma unroll
            for (int i = 0; i < 4; i++)
                #pragma unroll
                for (int rr = 0; rr < 4; rr++)
                    out[(size_t)(bm + i*16 + quad*4 + rr)*C + col] =
                        (__bf16)((acc[i][rr] + bsv) * (float)QSCALE);
        } else if (col < 512) {
            int hd = (col-256) >> 5, dh = (col-256) & 31;
            #pragma unroll
            for (int i = 0; i < 4; i++)
                #pragma unroll
                for (int rr = 0; rr < 4; rr++)
                    ktp[((size_t)hd*NN + bm + i*16 + quad*4 + rr)*DH + dh] =
                        (__bf16)(acc[i][rr] + bsv);
        } else {
            int vrow = col - 512;
            #pragma unroll
            for (int i = 0; i < 4; i++) {
                bf16x4v pk = {(__bf16)(acc[i][0]+bsv), (__bf16)(acc[i][1]+bsv),
                              (__bf16)(acc[i][2]+bsv), (__bf16)(acc[i][3]+bsv)};
                *(bf16x4v*)&vt[(size_t)vrow*NN + bm + i*16 + quad*4] = pk;
            }
        }
        return;
    }
    float bsv = b0[col];
    float sc1 = 0.f, sh1 = 0.f, sc2 = 0.f, sh2 = 0.f;
    if constexpr (BN == 2) {
        float m1 = st1[col]*(1.f/NN);
        sc1 = rsqrtf(st1[C+col]*(1.f/NN) - m1*m1 + EPS) * g1[col];
        sh1 = bb1[col] - m1*sc1;
        float m2 = st2[col]*(1.f/NN);
        sc2 = rsqrtf(st2[C+col]*(1.f/NN) - m2*m2 + EPS) * g2[col];
        sh2 = bb2[col] - m2*sc2;
    }
    float ssum = 0.f, ssq = 0.f;
    #pragma unroll
    for (int i = 0; i < 4; i++) {
        #pragma unroll
        for (int rr = 0; rr < 4; rr++) {
            int rw = bm + i*16 + quad*4 + rr;
            float vv = acc[i][rr] + bsv;
            if (relu) vv = fmaxf(vv, 0.f);
            size_t idx = (size_t)rw*Nout + col;
            if constexpr (BN == 2) {
                vv += (float)add1[idx]*sc1 + sh1 + (float)add2[idx]*sc2 + sh2;
            } else {
                if (add1) vv += (float)add1[idx];
                if (add2) vv += (float)add2[idx];
            }
            out[idx] = (__bf16)vv;
            ssum += vv; ssq += vv*vv;
        }
    }
    if (stats) {
        ssum += __shfl_xor(ssum, 16); ssum += __shfl_xor(ssum, 32);
        ssq  += __shfl_xor(ssq, 16);  ssq  += __shfl_xor(ssq, 32);
        if (quad == 0) {
            atomicAdd(&stats[col], ssum);
            atomicAdd(&stats[Nout + col], ssq);
        }
    }
}

// ---------------- attention body: 256-q tiles, SPLIT=4 (R25, unchanged) ----------------
__device__ __forceinline__ void attn_body(int t, const __bf16* __restrict__ qbuf,
        const __bf16* __restrict__ kt, const __bf16* __restrict__ vt,
        __bf16* __restrict__ opart, float* __restrict__ lsum, __bf16* lds) {
    int head = t & 7, qi = (t >> 3) & 15, z = t >> 7;
    int qb = qi * QB;
    int hb = head * DH;
    int tid = threadIdx.x;
    int wave = tid >> 6, lane = tid & 63;
    int ln = lane & 15, quad = lane >> 4;
    __bf16* Kb0 = lds;                    // [128][36] = 4608 elems each
    __bf16* Kb1 = lds + 4608;
    __bf16* Vb0 = lds + 9216;             // [32][VS] = 4352 elems each
    __bf16* Vb1 = lds + 9216 + 32*VS;

    bf16x8 qf[4];
    #pragma unroll
    for (int g = 0; g < 4; g++)
        qf[g] = *(const bf16x8*)&qbuf[(size_t)(qb + wave*64 + g*16 + ln)*C + hb + quad*8];

    f32x4 ot[4][2] = {};
    f32x4 la[4] = {};
    const bf16x4s ones = {(short)0x3F80, (short)0x3F80, (short)0x3F80, (short)0x3F80};
    const f32x4 zz = {0.f,0.f,0.f,0.f};

    int srow = tid >> 1, sseg = (tid & 1) * 16;   // K staging: 2 threads/row (64B rows)
    int vd = tid >> 3, vseg = (tid & 7) * 16;     // V staging: 8 threads/dim-row
    int kt0 = z * KT8;
    const __bf16* kbase = &kt[(size_t)head*NN*DH];
    {   // prologue: stage tile (rotated start decorrelates VMEM bursts)
        int i0 = qi & (KT8-1);
        const __bf16* kp = &kbase[(size_t)((kt0+i0)*128 + srow)*DH + sseg];
        *(bf16x8*)&Kb0[srow*36 + sseg]     = *(const bf16x8*)kp;
        *(bf16x8*)&Kb0[srow*36 + sseg + 8] = *(const bf16x8*)(kp + 8);
        const __bf16* vp = &vt[(size_t)(hb + vd)*NN + (kt0+i0)*128 + vseg];
        *(bf16x8*)&Vb0[vd*VS + vseg]     = *(const bf16x8*)vp;
        *(bf16x8*)&Vb0[vd*VS + vseg + 8] = *(const bf16x8*)(vp + 8);
    }
    for (int ii = 0; ii < KT8; ii++) {
        int inext = (ii + 1 + qi) & (KT8-1);
        __bf16* Kc = (ii & 1) ? Kb1 : Kb0;
        __bf16* Kn = (ii & 1) ? Kb0 : Kb1;
        __bf16* Vc = (ii & 1) ? Vb1 : Vb0;
        __bf16* Vn = (ii & 1) ? Vb0 : Vb1;
        __syncthreads();                       // Kc/Vc writes visible
        bf16x8 nk0, nk1, nv0, nv1;
        bool hasNext = (ii + 1 < KT8);
        if (hasNext) {                          // next-tile loads overlap compute
            const __bf16* kp = &kbase[(size_t)((kt0+inext)*128 + srow)*DH + sseg];
            nk0 = *(const bf16x8*)kp;
            nk1 = *(const bf16x8*)(kp + 8);
            const __bf16* vp = &vt[(size_t)(hb + vd)*NN + (kt0+inext)*128 + vseg];
            nv0 = *(const bf16x8*)vp;
            nv1 = *(const bf16x8*)(vp + 8);
        }
        #pragma unroll
        for (int pr = 0; pr < 4; pr++) {
            #pragma unroll
            for (int s = 0; s < 2; s++) {
                int ks = pr*2 + s;
                bf16x8 kf = *(const bf16x8*)&Kc[(ks*16+ln)*36 + quad*8];
                bf16x4s vf0 = *(const bf16x4s*)&Vc[(0*16+ln)*VS + ks*16 + quad*4];
                bf16x4s vf1 = *(const bf16x4s*)&Vc[(1*16+ln)*VS + ks*16 + quad*4];
                f32x4 st0 = __builtin_amdgcn_mfma_f32_16x16x32_bf16(kf, qf[0], zz, 0, 0, 0);
                f32x4 st1 = __builtin_amdgcn_mfma_f32_16x16x32_bf16(kf, qf[1], zz, 0, 0, 0);
                f32x4 st2 = __builtin_amdgcn_mfma_f32_16x16x32_bf16(kf, qf[2], zz, 0, 0, 0);
                f32x4 st3 = __builtin_amdgcn_mfma_f32_16x16x32_bf16(kf, qf[3], zz, 0, 0, 0);
                union { __bf16 b[4]; bf16x4s s; } pf0, pf1, pf2, pf3;
                #pragma unroll
                for (int rr = 0; rr < 4; rr++) {
                    pf0.b[rr] = (__bf16)__builtin_amdgcn_exp2f(st0[rr]);
                    pf1.b[rr] = (__bf16)__builtin_amdgcn_exp2f(st1[rr]);
                    pf2.b[rr] = (__bf16)__builtin_amdgcn_exp2f(st2[rr]);
                    pf3.b[rr] = (__bf16)__builtin_amdgcn_exp2f(st3[rr]);
                }
                ot[0][0] = __builtin_amdgcn_mfma_f32_16x16x16bf16_1k(vf0, pf0.s, ot[0][0], 0, 0, 0);
                ot[0][1] = __builtin_amdgcn_mfma_f32_16x16x16bf16_1k(vf1, pf0.s, ot[0][1], 0, 0, 0);
                ot[1][0] = __builtin_amdgcn_mfma_f32_16x16x16bf16_1k(vf0, pf1.s, ot[1][0], 0, 0, 0);
                ot[1][1] = __builtin_amdgcn_mfma_f32_16x16x16bf16_1k(vf1, pf1.s, ot[1][1], 0, 0, 0);
                ot[2][0] = __builtin_amdgcn_mfma_f32_16x16x16bf16_1k(vf0, pf2.s, ot[2][0], 0, 0, 0);
                ot[2][1] = __builtin_amdgcn_mfma_f32_16x16x16bf16_1k(vf1, pf2.s, ot[2][1], 0, 0, 0);
                ot[3][0] = __builtin_amdgcn_mfma_f32_16x16x16bf16_1k(vf0, pf3.s, ot[3][0], 0, 0, 0);
                ot[3][1] = __builtin_amdgcn_mfma_f32_16x16x16bf16_1k(vf1, pf3.s, ot[3][1], 0, 0, 0);
                la[0]    = __builtin_amdgcn_mfma_f32_16x16x16bf16_1k(ones, pf0.s, la[0], 0, 0, 0);
                la[1]    = __builtin_amdgcn_mfma_f32_16x16x16bf16_1k(ones, pf1.s, la[1], 0, 0, 0);
                la[2]    = __builtin_amdgcn_mfma_f32_16x16x16bf16_1k(ones, pf2.s, la[2], 0, 0, 0);
                la[3]    = __builtin_amdgcn_mfma_f32_16x16x16bf16_1k(ones, pf3.s, la[3], 0, 0, 0);
            }
        }
        if (hasNext) {
            *(bf16x8*)&Kn[srow*36 + sseg]     = nk0;
            *(bf16x8*)&Kn[srow*36 + sseg + 8] = nk1;
            *(bf16x8*)&Vn[vd*VS + vseg]     = nv0;
            *(bf16x8*)&Vn[vd*VS + vseg + 8] = nv1;
        }
    }
    #pragma unroll
    for (int g = 0; g < 4; g++) {
        float l_ = la[g][0];
        float inv = 1.0f / l_;
        int qrow = qb + wave*64 + g*16 + ln;
        #pragma unroll
        for (int h = 0; h < 2; h++) {
            bf16x4v pk = {(__bf16)(ot[g][h][0]*inv), (__bf16)(ot[g][h][1]*inv),
                          (__bf16)(ot[g][h][2]*inv), (__bf16)(ot[g][h][3]*inv)};
            *(bf16x4v*)&opart[((size_t)z*NN + qrow)*C + hb + h*16 + quad*4] = pk;
        }
        if (quad == 0)
            lsum[((size_t)z*NH + head)*NN + qrow] = l_;
    }
}

// ---------------- kernel 1: stacked-QKV gemm + CSR gather agg ----------------
__global__ __launch_bounds__(256) void qkv_agg_kernel(const __bf16* __restrict__ Hb,
        const __bf16* __restrict__ Wqkv, const float* __restrict__ bq,
        const float* __restrict__ bk, const float* __restrict__ bv,
        __bf16* __restrict__ qout, __bf16* __restrict__ ktout,
        __bf16* __restrict__ vtout,
        const int* __restrict__ rowptr, const int* __restrict__ eidsrc,
        float* __restrict__ agg) {
    __shared__ __bf16 lds[9216];
    int bx = blockIdx.x;
    if (bx < 768) {
        gemm_core<1,0,0>((bx & 63)*64, (bx >> 6)*64, Hb, nullptr, nullptr, Wqkv,
                bq, bk, bv, nullptr, nullptr, qout, vtout, ktout, nullptr,
                nullptr, nullptr, nullptr, nullptr, nullptr, nullptr, nullptr,
                nullptr, C, 768, 0, lds, lds + 4608);
        return;
    }
    int tid = threadIdx.x;
    int wave = tid >> 6, lane = tid & 63;
    int node = (bx - 768)*4 + wave;
    int beg = rowptr[node], end = rowptr[node+1];
    float s0 = 0.f, s1 = 0.f, s2 = 0.f, s3 = 0.f;
    for (int e = beg; e < end; e++) {
        int src = eidsrc[e];
        bf16x4v hv = *(const bf16x4v*)&Hb[(size_t)src*C + lane*4];
        s0 += (float)hv[0]; s1 += (float)hv[1];
        s2 += (float)hv[2]; s3 += (float)hv[3];
    }
    float4 o = {s0, s1, s2, s3};
    *(float4*)&agg[(size_t)node*C + lane*4] = o;
}

// ---------------- kernel 2: GIN gemm1 (first, drains early) + attention ----------------
// launch_bounds (256,2): cap 256 VGPR for the 256-q attn (~170 needed), 2 blocks/CU
__global__ __launch_bounds__(256, 2) void gin1_attn_kernel(const __bf16* __restrict__ Hb,
        const float* __restrict__ agg, const __bf16* __restrict__ gw1,
        const float* __restrict__ gb1, __bf16* __restrict__ t1,
        const __bf16* __restrict__ qbuf, const __bf16* __restrict__ kt,
        const __bf16* __restrict__ vt,
        __bf16* __restrict__ opart, float* __restrict__ lsum) {
    __shared__ __bf16 lds[17920];     // attn: K dbuf 9216 + V dbuf 8704; gemm: 9216
    int bx = blockIdx.x;
    if (bx < 256) {
        gemm_core<0,0,0>((bx >> 2)*64, (bx & 3)*64, Hb, agg, nullptr, gw1,
                gb1, nullptr, nullptr, nullptr, nullptr, t1, nullptr, nullptr,
                nullptr, nullptr, nullptr, nullptr, nullptr, nullptr, nullptr,
                nullptr, nullptr, C, C, 1, lds, lds + 4608);
        return;
    }
    attn_body(bx - 256, qbuf, kt, vt, opart, lsum, lds);
}

// ---------------- kernel 3: GIN gemm2 + proj-with-combine (independent) ----------------
__global__ __launch_bounds__(256) void gin2_proj_kernel(const __bf16* __restrict__ t1,
        const __bf16* __restrict__ gw2, const float* __restrict__ gb2,
        const __bf16* __restrict__ Hb, __bf16* __restrict__ z1, float* __restrict__ st1,
        const __bf16* __restrict__ opart, const float* __restrict__ lsum,
        const __bf16* __restrict__ wop, const float* __restrict__ lbo,
        __bf16* __restrict__ z2, float* __restrict__ st2) {
    __shared__ __bf16 lds[9216];
    int bx = blockIdx.x;
    if (bx < 256) {
        gemm_core<0,0,0>((bx >> 2)*64, (bx & 3)*64, t1, nullptr, nullptr, gw2,
                gb2, nullptr, nullptr, Hb, nullptr, z1, nullptr, nullptr, st1,
                nullptr, nullptr, nullptr, nullptr, nullptr, nullptr, nullptr,
                nullptr, C, C, 0, lds, lds + 4608);
        return;
    }
    int t = bx - 256;
    gemm_core<0,0,1>((t >> 2)*64, (t & 3)*64, opart, nullptr, nullptr, wop,
            lbo, nullptr, nullptr, Hb, nullptr, z2, nullptr, nullptr, st2,
            nullptr, nullptr, nullptr, nullptr, nullptr, nullptr, nullptr,
            lsum, C, C, 0, lds, lds + 4608);
}

// ---------------- kernel 4: ff1 with inline bn1/bn2 on staging ----------------
__global__ __launch_bounds__(256) void ff1_kernel(const __bf16* __restrict__ z1,
        const __bf16* __restrict__ z2, const __bf16* __restrict__ mw1,
        const float* __restrict__ lmb1, __bf16* __restrict__ hidden,
        const float* __restrict__ st1, const float* __restrict__ g1,
        const float* __restrict__ bb1, const float* __restrict__ st2,
        const float* __restrict__ g2, const float* __restrict__ bb2) {
    __shared__ __bf16 lds[9216];
    __shared__ float coefs[4*C];
    int tid = threadIdx.x;
    {   // fold BN stats -> (scale, shift) per channel, in LDS
        float m = st1[tid]*(1.f/NN);
        float var = st1[C+tid]*(1.f/NN) - m*m;
        float s = rsqrtf(var + EPS) * g1[tid];
        coefs[tid] = s; coefs[C+tid] = bb1[tid] - m*s;
        m = st2[tid]*(1.f/NN);
        var = st2[C+tid]*(1.f/NN) - m*m;
        s = rsqrtf(var + EPS) * g2[tid];
        coefs[2*C+tid] = s; coefs[3*C+tid] = bb2[tid] - m*s;
    }
    __syncthreads();   // staging reads coefs BEFORE gemm_core's first barrier
    int bx = blockIdx.x;
    gemm_core<0,1,0>((bx >> 3)*64, (bx & 7)*64, z1, nullptr, z2, mw1,
            lmb1, nullptr, nullptr, nullptr, nullptr, hidden, nullptr, nullptr,
            nullptr, coefs, nullptr, nullptr, nullptr, nullptr, nullptr, nullptr,
            nullptr, C, 2*C, 1, lds, lds + 4608);
}

// ---------------- kernel 5: ff2 with inline bn residuals in epilogue ----------------
__global__ __launch_bounds__(256) void ff2_kernel(const __bf16* __restrict__ hidden,
        const __bf16* __restrict__ mw2, const float* __restrict__ lmb2,
        const __bf16* __restrict__ z1, const __bf16* __restrict__ z2,
        __bf16* __restrict__ zbuf3, float* __restrict__ st3,
        const float* __restrict__ st1, const float* __restrict__ g1,
        const float* __restrict__ bb1, const float* __restrict__ st2,
        const float* __restrict__ g2, const float* __restrict__ bb2) {
    __shared__ __bf16 lds[9216];
    int bx = blockIdx.x;
    gemm_core<0,2,0>((bx >> 2)*64, (bx & 3)*64, hidden, nullptr, nullptr, mw2,
            lmb2, nullptr, nullptr, z1, z2, zbuf3, nullptr, nullptr, st3,
            nullptr, st1, g1, bb1, st2, g2, bb2,
            nullptr, 2*C, C, 0, lds, lds + 4608);
}

// ---------------- BatchNorm apply (bn3 only) ----------------
__global__ __launch_bounds__(256) void bn_apply_kernel(const __bf16* __restrict__ z,
        const float* __restrict__ stats, const float* __restrict__ g,
        const float* __restrict__ b, __bf16* __restrict__ outb,
        float* __restrict__ outf) {
    int idx4 = (blockIdx.x*256 + threadIdx.x) * 4;
    int c = idx4 & (C-1);
    bf16x4v zv = *(const bf16x4v*)&z[idx4];
    float4 st = *(const float4*)&stats[c];
    float4 sq = *(const float4*)&stats[C + c];
    float4 gv = *(const float4*)&g[c];
    float4 bv = *(const float4*)&b[c];
    float o[4];
    float m0 = st.x*(1.f/NN), m1 = st.y*(1.f/NN), m2 = st.z*(1.f/NN), m3 = st.w*(1.f/NN);
    o[0] = ((float)zv[0] - m0) * rsqrtf(sq.x*(1.f/NN) - m0*m0 + EPS) * gv.x + bv.x;
    o[1] = ((float)zv[1] - m1) * rsqrtf(sq.y*(1.f/NN) - m1*m1 + EPS) * gv.y + bv.y;
    o[2] = ((float)zv[2] - m2) * rsqrtf(sq.z*(1.f/NN) - m2*m2 + EPS) * gv.z + bv.z;
    o[3] = ((float)zv[3] - m3) * rsqrtf(sq.w*(1.f/NN) - m3*m3 + EPS) * gv.w + bv.w;
    if (outb) {
        bf16x4v ov = {(__bf16)o[0], (__bf16)o[1], (__bf16)o[2], (__bf16)o[3]};
        *(bf16x4v*)&outb[idx4] = ov;
    } else {
        float4 ov = {o[0], o[1], o[2], o[3]};
        *(float4*)&outf[idx4] = ov;
    }
}

extern "C" void kernel_launch(void* const* d_in, const int* in_sizes, int n_in,
                              void* d_out, int out_size, void* d_ws, size_t ws_size,
                              hipStream_t stream) {
    const float* x      = (const float*)d_in[0];
    const int*   ei     = (const int*)d_in[1];
    const float* lin1_w = (const float*)d_in[2];
    const float* lin1_b = (const float*)d_in[3];
    const float* gin_w1 = (const float*)d_in[4];
    const float* gin_b1 = (const float*)d_in[5];
    const float* gin_w2 = (const float*)d_in[6];
    const float* gin_b2 = (const float*)d_in[7];
    const float* wq = (const float*)d_in[8];
    const float* wk = (const float*)d_in[9];
    const float* wv = (const float*)d_in[10];
    const float* wo = (const float*)d_in[11];
    const float* bq = (const float*)d_in[12];
    const float* bk = (const float*)d_in[13];
    const float* bv = (const float*)d_in[14];
    const float* bo = (const float*)d_in[15];
    const float* bn1_g = (const float*)d_in[16];
    const float* bn1_b = (const float*)d_in[17];
    const float* bn2_g = (const float*)d_in[18];
    const float* bn2_b = (const float*)d_in[19];
    const float* bn3_g = (const float*)d_in[20];
    const float* bn3_b = (const float*)d_in[21];
    const float* mw1 = (const float*)d_in[22];
    const float* mb1 = (const float*)d_in[23];
    const float* mw2 = (const float*)d_in[24];
    const float* mb2 = (const float*)d_in[25];

    const size_t MB = 1u << 20;
    char* ws = (char*)d_ws;
    __bf16* Hb      = (__bf16*)(ws);            // 2 MB  layer input
    __bf16* z1      = (__bf16*)(ws + 2*MB);     // 2 MB  GIN pre-bn1
    __bf16* zbuf3   = (__bf16*)(ws + 4*MB);     // 2 MB  pre-bn3
    __bf16* z2      = (__bf16*)(ws + 6*MB);     // 2 MB  attn pre-bn2
    __bf16* t1      = (__bf16*)(ws + 8*MB);     // 2 MB  GIN hidden
    __bf16* Qbuf    = (__bf16*)(ws + 10*MB);    // 2 MB  [N][C] (QSCALE folded)
    __bf16* Ktb     = (__bf16*)(ws + 12*MB);    // 2 MB  [NH][NN][DH] head-major K
    __bf16* Vt      = (__bf16*)(ws + 14*MB);    // 2 MB  [C][N]
    float*  agg     = (float*)(ws + 16*MB);     // 4 MB  (dead after gin1)
    __bf16* hiddenb = (__bf16*)(ws + 16*MB);    // 4 MB  shares agg region (agg dead
                                                //       after gin1; hidden lives k4->k5,
                                                //       agg rewritten next layer k1)
    __bf16* Opart   = (__bf16*)(ws + 20*MB);    // 8 MB  (SPLIT=4)
    __bf16* Wb      = (__bf16*)(ws + 28*MB);    // 3.93 MB
    float*  stats   = (float*)(ws + 32*MB);     // 9 x 2C
    int*    cursor  = (int*)(ws + 32*MB + 64*1024);
    int*    rowptr  = (int*)(ws + 32*MB + 96*1024);
    int*    eidsrc  = (int*)(ws + 32*MB + 128*1024);
    float*  lsum    = (float*)(ws + 33*MB);     // 0.5 MB (SPLIT=4), dedicated

    dim3 blk(256);

    prep_w<<<dim3(384, 8), blk, 0, stream>>>(gin_w1, gin_w2, wq, wk, wv, wo, mw1, mw2, Wb);
    hipMemsetAsync(stats, 0, 9 * 2 * C * sizeof(float), stream);
    lin1_kernel<<<NN, blk, 0, stream>>>(x, lin1_w, lin1_b, Hb);
    hipMemsetAsync(cursor, 0, NN * sizeof(int), stream);
    hist_kernel<<<NE/256, blk, 0, stream>>>(ei, cursor);
    scan_kernel<<<1, blk, 0, stream>>>(cursor, rowptr, cursor);
    fill_kernel<<<NE/256, blk, 0, stream>>>(ei, cursor, eidsrc);

    for (int l = 0; l < NL; l++) {
        const __bf16* gw1b = Wb + (size_t)l*CC1;
        const __bf16* gw2b = Wb + (size_t)(3+l)*CC1;
        const __bf16* wqkv = Wb + (size_t)(6+3*l)*CC1;
        const __bf16* wop  = Wb + (size_t)(15+l)*CC1;
        const __bf16* mw1p = Wb + (size_t)(18+2*l)*CC1;
        const __bf16* mw2p = Wb + (size_t)(24+2*l)*CC1;
        const float* gb1 = gin_b1 + (size_t)l*C;
        const float* gb2 = gin_b2 + (size_t)l*C;
        const float* lbq = bq + (size_t)l*C;
        const float* lbk = bk + (size_t)l*C;
        const float* lbv = bv + (size_t)l*C;
        const float* lbo = bo + (size_t)l*C;
        const float* lmb1 = mb1 + (size_t)l*2*C;
        const float* lmb2 = mb2 + (size_t)l*C;
        float* st1 = stats + (size_t)l*3*2*C;
        float* st2 = st1 + 2*C;
        float* st3 = st2 + 2*C;
        const float* g1v = bn1_g + (size_t)l*C; const float* b1v = bn1_b + (size_t)l*C;
        const float* g2v = bn2_g + (size_t)l*C; const float* b2v = bn2_b + (size_t)l*C;

        // 1. stacked-QKV projection (Q / head-major K / V^T) + gather aggregation
        qkv_agg_kernel<<<768 + NN/4, blk, 0, stream>>>(Hb, wqkv, lbq, lbk, lbv,
                Qbuf, Ktb, Vt, rowptr, eidsrc, agg);
        // 2. GIN gemm1 (first, drains early) + flash attention (256-q, SPLIT=4)
        gin1_attn_kernel<<<256 + ATTN_BLKS, blk, 0, stream>>>(Hb, agg,
                gw1b, gb1, t1, Qbuf, Ktb, Vt, Opart, lsum);
        // 3. GIN gemm2 + proj-with-inline-combine (independent)
        gin2_proj_kernel<<<512, blk, 0, stream>>>(t1, gw2b, gb2, Hb, z1, st1,
                Opart, lsum, wop, lbo, z2, st2);
        // 4. ff1: bn1(z1)+bn2(z2) folded into staging
        ff1_kernel<<<512, blk, 0, stream>>>(z1, z2, mw1p, lmb1, hiddenb,
                st1, g1v, b1v, st2, g2v, b2v);
        // 5. ff2: bn residuals in epilogue
        ff2_kernel<<<256, blk, 0, stream>>>(hiddenb, mw2p, lmb2, z1, z2,
                zbuf3, st3, st1, g1v, b1v, st2, g2v, b2v);
        // 6. bn3
        if (l == NL-1)
            bn_apply_kernel<<<NN/4, blk, 0, stream>>>(zbuf3, st3,
                    bn3_g + (size_t)l*C, bn3_b + (size_t)l*C, nullptr, (float*)d_out);
        else
            bn_apply_kernel<<<NN/4, blk, 0, stream>>>(zbuf3, st3,
                    bn3_g + (size_t)l*C, bn3_b + (size_t)l*C, Hb, nullptr);
    }
}